// Round 1
// baseline (1583.454 us; speedup 1.0000x reference)
//
#include <hip/hip_runtime.h>
#include <math.h>

typedef unsigned short u16;
typedef __attribute__((ext_vector_type(8))) unsigned short us8v;

static __device__ __forceinline__ float bf2f(u16 u) {
  union { unsigned int i; float f; } v; v.i = ((unsigned int)u) << 16; return v.f;
}
static __device__ __forceinline__ u16 f2bf(float f) {
  union { float f; unsigned int i; } v; v.f = f;
  unsigned int i = v.i;
  unsigned int r = (i + 0x7FFFu + ((i >> 16) & 1u)) >> 16;
  return (u16)r;
}
static __device__ __forceinline__ float gelu_f(float x) {
  return 0.5f * x * (1.0f + erff(x * 0.70710678118654752f));
}
static __device__ __forceinline__ void f4arr(float4 v, float* a) {
  a[0] = v.x; a[1] = v.y; a[2] = v.z; a[3] = v.w;
}
static __device__ __forceinline__ void bf4arr(ushort4 v, float* a) {
  a[0] = bf2f(v.x); a[1] = bf2f(v.y); a[2] = bf2f(v.z); a[3] = bf2f(v.w);
}

#define NTOK 147456  // H*W = 384*384
#define NWX 48       // windows per row/col

// ---------------------------------------------------------------------------
// Kernel 1: LN1 + windowed MHSA + proj + residual -> x1 (one block per window)
// ---------------------------------------------------------------------------
__global__ __launch_bounds__(256) void k_attn(
    const float* __restrict__ x,
    const float* __restrict__ n1g, const float* __restrict__ n1b,
    const float* __restrict__ wq, const float* __restrict__ bq,
    const float* __restrict__ wkv, const float* __restrict__ bkv,
    const float* __restrict__ relb,
    const float* __restrict__ wproj, const float* __restrict__ bproj,
    float* __restrict__ x1)
{
  __shared__ float xs[64][68];   // LN1 output
  __shared__ float qs[64][68];   // q [token][c]
  __shared__ float ksm[64][68];  // k [token][c]
  __shared__ float vT[64][68];   // v transposed: [c][token]
  __shared__ float Ss[64][68];   // scores / probs (per head)
  __shared__ float osm[64][68];  // attn out [token][c]
  __shared__ u16 wqs[64 * 64];
  __shared__ u16 wkvs[64 * 128];
  __shared__ u16 wps[64 * 64];
  __shared__ float red[2][4][64];

  const int tid = threadIdx.x;
  const int blk = blockIdx.x;
  const int b = blk / 2304;
  const int rem = blk - b * 2304;
  const int wy = rem / NWX, wx = rem - wy * NWX;

  // stage weights to LDS as bf16
  for (int i = tid; i < 64 * 64; i += 256) wqs[i] = f2bf(wq[i]);
  for (int i = tid; i < 64 * 128; i += 256) wkvs[i] = f2bf(wkv[i]);
  for (int i = tid; i < 64 * 64; i += 256) wps[i] = f2bf(wproj[i]);

  // ---- load window + LN1 ----
  const int t = tid >> 2, g = tid & 3;      // token, quarter (16 ch each)
  const int gy = wy * 8 + (t >> 3), gx = wx * 8 + (t & 7);
  const long rowbase = ((long)b * NTOK + gy * 384 + gx) * 64;
  float loc[16];
  {
    float s0 = 0.f, s1 = 0.f;
#pragma unroll
    for (int k = 0; k < 16; k += 4) {
      float4 v4 = *reinterpret_cast<const float4*>(x + rowbase + g * 16 + k);
      loc[k] = v4.x; loc[k + 1] = v4.y; loc[k + 2] = v4.z; loc[k + 3] = v4.w;
    }
#pragma unroll
    for (int k = 0; k < 16; ++k) { s0 += loc[k]; s1 += loc[k] * loc[k]; }
    red[0][g][t] = s0; red[1][g][t] = s1;
  }
  __syncthreads();
  {
    float m = (red[0][0][t] + red[0][1][t] + red[0][2][t] + red[0][3][t]) * 0.015625f;
    float var = (red[1][0][t] + red[1][1][t] + red[1][2][t] + red[1][3][t]) * 0.015625f - m * m;
    float rs = rsqrtf(var + 1e-5f);
#pragma unroll
    for (int k = 0; k < 16; ++k) {
      int c = g * 16 + k;
      xs[t][c] = (loc[k] - m) * rs * n1g[c] + n1b[c];
    }
  }
  __syncthreads();

  const int t4 = (tid >> 4) * 4;   // token tile base
  const int o4 = (tid & 15) * 4;   // out-channel tile base

  // ---- QKV ----
  {
    float aq[4][4] = {}, ak[4][4] = {}, av[4][4] = {};
    for (int c4 = 0; c4 < 64; c4 += 4) {
      float xa[4][4];
#pragma unroll
      for (int j = 0; j < 4; ++j)
        f4arr(*reinterpret_cast<const float4*>(&xs[t4 + j][c4]), xa[j]);
#pragma unroll
      for (int cc = 0; cc < 4; ++cc) {
        const int c = c4 + cc;
        float wqf[4], wkf[4], wvf[4];
        bf4arr(*reinterpret_cast<const ushort4*>(&wqs[c * 64 + o4]), wqf);
        bf4arr(*reinterpret_cast<const ushort4*>(&wkvs[c * 128 + o4]), wkf);
        bf4arr(*reinterpret_cast<const ushort4*>(&wkvs[c * 128 + 64 + o4]), wvf);
#pragma unroll
        for (int j = 0; j < 4; ++j) {
          float a = xa[j][cc];
#pragma unroll
          for (int k = 0; k < 4; ++k) {
            aq[j][k] += a * wqf[k];
            ak[j][k] += a * wkf[k];
            av[j][k] += a * wvf[k];
          }
        }
      }
    }
#pragma unroll
    for (int j = 0; j < 4; ++j)
#pragma unroll
      for (int k = 0; k < 4; ++k) {
        qs[t4 + j][o4 + k]  = aq[j][k] + bq[o4 + k];
        ksm[t4 + j][o4 + k] = ak[j][k] + bkv[o4 + k];
        vT[o4 + k][t4 + j]  = av[j][k] + bkv[64 + o4 + k];
      }
  }
  __syncthreads();

  // ---- per-head attention ----
#pragma unroll 1
  for (int hh = 0; hh < 2; ++hh) {
    const int hc = hh * 32;
    {
      const int i4 = (tid >> 4) * 4, j4 = (tid & 15) * 4;
      float acc[4][4] = {};
      for (int c4 = 0; c4 < 32; c4 += 4) {
        float qa[4][4], ka[4][4];
#pragma unroll
        for (int ii = 0; ii < 4; ++ii)
          f4arr(*reinterpret_cast<const float4*>(&qs[i4 + ii][hc + c4]), qa[ii]);
#pragma unroll
        for (int jj = 0; jj < 4; ++jj)
          f4arr(*reinterpret_cast<const float4*>(&ksm[j4 + jj][hc + c4]), ka[jj]);
#pragma unroll
        for (int cc = 0; cc < 4; ++cc)
#pragma unroll
          for (int ii = 0; ii < 4; ++ii)
#pragma unroll
            for (int jj = 0; jj < 4; ++jj)
              acc[ii][jj] += qa[ii][cc] * ka[jj][cc];
      }
#pragma unroll
      for (int ii = 0; ii < 4; ++ii)
#pragma unroll
        for (int jj = 0; jj < 4; ++jj) {
          int i = i4 + ii, j = j4 + jj;
          int dy = (i >> 3) - (j >> 3) + 7;
          int dx = (i & 7) - (j & 7) + 7;
          Ss[i][j] = acc[ii][jj] * 0.17677669529663687f + relb[(dy * 15 + dx) * 2 + hh];
        }
    }
    __syncthreads();
    // softmax (wave 0, one row per lane)
    if (tid < 64) {
      float mx = -1e30f;
      for (int j = 0; j < 64; ++j) mx = fmaxf(mx, Ss[tid][j]);
      float sum = 0.f;
      for (int j = 0; j < 64; ++j) { float e = expf(Ss[tid][j] - mx); Ss[tid][j] = e; sum += e; }
      float inv = 1.f / sum;
      for (int j = 0; j < 64; ++j) Ss[tid][j] *= inv;
    }
    __syncthreads();
    // P @ V
    {
      const int i4 = (tid >> 4) * 4, d2 = (tid & 15) * 2;
      float acc[4][2] = {};
      for (int j4 = 0; j4 < 64; j4 += 4) {
        float pr[4][4];
#pragma unroll
        for (int ii = 0; ii < 4; ++ii)
          f4arr(*reinterpret_cast<const float4*>(&Ss[i4 + ii][j4]), pr[ii]);
        float va[4], vb[4];
        f4arr(*reinterpret_cast<const float4*>(&vT[hc + d2][j4]), va);
        f4arr(*reinterpret_cast<const float4*>(&vT[hc + d2 + 1][j4]), vb);
#pragma unroll
        for (int ii = 0; ii < 4; ++ii) {
          acc[ii][0] += pr[ii][0] * va[0] + pr[ii][1] * va[1] + pr[ii][2] * va[2] + pr[ii][3] * va[3];
          acc[ii][1] += pr[ii][0] * vb[0] + pr[ii][1] * vb[1] + pr[ii][2] * vb[2] + pr[ii][3] * vb[3];
        }
      }
#pragma unroll
      for (int ii = 0; ii < 4; ++ii) {
        osm[i4 + ii][hc + d2]     = acc[ii][0];
        osm[i4 + ii][hc + d2 + 1] = acc[ii][1];
      }
    }
    __syncthreads();
  }

  // ---- proj + residual -> x1 ----
  {
    float acc[4][4] = {};
    for (int c4 = 0; c4 < 64; c4 += 4) {
      float oa[4][4];
#pragma unroll
      for (int j = 0; j < 4; ++j)
        f4arr(*reinterpret_cast<const float4*>(&osm[t4 + j][c4]), oa[j]);
#pragma unroll
      for (int cc = 0; cc < 4; ++cc) {
        float wf[4];
        bf4arr(*reinterpret_cast<const ushort4*>(&wps[(c4 + cc) * 64 + o4]), wf);
#pragma unroll
        for (int j = 0; j < 4; ++j)
#pragma unroll
          for (int k = 0; k < 4; ++k)
            acc[j][k] += oa[j][cc] * wf[k];
      }
    }
#pragma unroll
    for (int j = 0; j < 4; ++j) {
      const int tt = t4 + j;
      const int gy2 = wy * 8 + (tt >> 3), gx2 = wx * 8 + (tt & 7);
      const long base2 = ((long)b * NTOK + gy2 * 384 + gx2) * 64 + o4;
      float4 xv = *reinterpret_cast<const float4*>(x + base2);
      float4 ov;
      ov.x = xv.x + acc[j][0] + bproj[o4 + 0];
      ov.y = xv.y + acc[j][1] + bproj[o4 + 1];
      ov.z = xv.z + acc[j][2] + bproj[o4 + 2];
      ov.w = xv.w + acc[j][3] + bproj[o4 + 3];
      *reinterpret_cast<float4*>(x1 + base2) = ov;
    }
  }
}

// ---------------------------------------------------------------------------
// Kernel 2: LN2 + fc1 + gelu + depthwise3x3 + gelu + fc2 + residual -> out
// One block per 8x8 spatial tile (with 1-token halo), fully fused in LDS.
// ---------------------------------------------------------------------------
__global__ __launch_bounds__(256) void k_mlp(
    const float* __restrict__ x1,
    const float* __restrict__ n2g, const float* __restrict__ n2b,
    const float* __restrict__ w1, const float* __restrict__ b1,
    const float* __restrict__ dwk, const float* __restrict__ dwb,
    const float* __restrict__ w2, const float* __restrict__ b2,
    float* __restrict__ out)
{
  __shared__ u16 ht[100 * 256];                // h tile (10x10 tokens, bf16)
  __shared__ __align__(16) char pool[67584];   // overlaid regions
  float* xsp = (float*)pool;                   // [100][68] f32  (phase A)
  u16* w1s = (u16*)(pool + 27200);             // [64*256] bf16  (phase A)
  u16* g2  = (u16*)pool;                       // [64*256] bf16  (phase B/C)
  u16* w2s = (u16*)(pool + 32768);             // [256][68] bf16 (phase C)

  const int tid = threadIdx.x;
  const int blk = blockIdx.x;
  const int b = blk / 2304;
  const int rem = blk - b * 2304;
  const int ty0 = (rem / NWX) * 8, tx0 = (rem - (rem / NWX) * NWX) * 8;
  const int wave = tid >> 6, lane = tid & 63;

  // stage w1 (bf16)
  for (int i = tid; i < 64 * 256; i += 256) w1s[i] = f2bf(w1[i]);

  // ---- A1: LN2 over 10x10 halo tile (one wave per token) ----
  {
    const float gg = n2g[lane], bb = n2b[lane];
    for (int it = 0; it < 25; ++it) {
      const int p = it * 4 + wave;
      const int py = ty0 + p / 10 - 1;
      const int px = tx0 + (p - (p / 10) * 10) - 1;
      float v = 0.f;
      if (py >= 0 && py < 384 && px >= 0 && px < 384) {  // wave-uniform branch
        float xv = x1[((long)b * NTOK + py * 384 + px) * 64 + lane];
        float sum = xv, sq = xv * xv;
#pragma unroll
        for (int off = 32; off >= 1; off >>= 1) {
          sum += __shfl_xor(sum, off);
          sq  += __shfl_xor(sq, off);
        }
        float m = sum * 0.015625f;
        float var = sq * 0.015625f - m * m;
        v = (xv - m) * rsqrtf(var + 1e-5f) * gg + bb;
      }
      xsp[p * 68 + lane] = v;
    }
  }
  __syncthreads();

  // ---- A2: fc1 + gelu -> ht (OOB halo rows forced to 0) ----
  for (int jb = tid; jb < 1600; jb += 256) {
    const int tg = jb >> 6;          // token group 0..24
    const int og = (jb & 63) * 4;    // out channel base 0..252
    float acc[4][4];
    float bv[4] = { b1[og], b1[og + 1], b1[og + 2], b1[og + 3] };
#pragma unroll
    for (int j = 0; j < 4; ++j)
#pragma unroll
      for (int k = 0; k < 4; ++k) acc[j][k] = bv[k];
    for (int c4 = 0; c4 < 64; c4 += 4) {
      float xa[4][4];
#pragma unroll
      for (int j = 0; j < 4; ++j)
        f4arr(*reinterpret_cast<const float4*>(&xsp[(tg * 4 + j) * 68 + c4]), xa[j]);
#pragma unroll
      for (int cc = 0; cc < 4; ++cc) {
        float wf[4];
        bf4arr(*reinterpret_cast<const ushort4*>(&w1s[(c4 + cc) * 256 + og]), wf);
#pragma unroll
        for (int j = 0; j < 4; ++j)
#pragma unroll
          for (int k = 0; k < 4; ++k)
            acc[j][k] += xa[j][cc] * wf[k];
      }
    }
#pragma unroll
    for (int j = 0; j < 4; ++j) {
      const int p = tg * 4 + j;
      const int py = ty0 + p / 10 - 1;
      const int px = tx0 + (p - (p / 10) * 10) - 1;
      const bool oob = (py < 0 || py >= 384 || px < 0 || px >= 384);
#pragma unroll
      for (int k = 0; k < 4; ++k)
        ht[p * 256 + og + k] = oob ? (u16)0 : f2bf(gelu_f(acc[j][k]));
    }
  }
  __syncthreads();

  // ---- B: stage w2 (bf16, padded rows) + depthwise conv 3x3 + gelu -> g2 ----
  for (int i = tid; i < 256 * 64; i += 256) {
    int c = i >> 6, oc = i & 63;
    w2s[c * 68 + oc] = f2bf(w2[i]);
  }
  {
    const int ch = (tid & 63) * 4;
    float wk[4][9];
    float bb4[4];
#pragma unroll
    for (int k = 0; k < 4; ++k) {
      bb4[k] = dwb[ch + k];
#pragma unroll
      for (int q = 0; q < 9; ++q) wk[k][q] = dwk[(ch + k) * 9 + q];
    }
    for (int tk = 0; tk < 16; ++tk) {
      const int token = wave * 16 + tk;
      const int ty = token >> 3, tx = token & 7;
      float acc[4] = { bb4[0], bb4[1], bb4[2], bb4[3] };
#pragma unroll
      for (int dy = 0; dy < 3; ++dy)
#pragma unroll
        for (int dx = 0; dx < 3; ++dx) {
          const int p = (ty + dy) * 10 + (tx + dx);
          ushort4 hv = *reinterpret_cast<const ushort4*>(&ht[p * 256 + ch]);
          const int q = dy * 3 + dx;
          acc[0] += bf2f(hv.x) * wk[0][q];
          acc[1] += bf2f(hv.y) * wk[1][q];
          acc[2] += bf2f(hv.z) * wk[2][q];
          acc[3] += bf2f(hv.w) * wk[3][q];
        }
      g2[token * 256 + ch + 0] = f2bf(gelu_f(acc[0]));
      g2[token * 256 + ch + 1] = f2bf(gelu_f(acc[1]));
      g2[token * 256 + ch + 2] = f2bf(gelu_f(acc[2]));
      g2[token * 256 + ch + 3] = f2bf(gelu_f(acc[3]));
    }
  }
  __syncthreads();

  // ---- C: fc2 + residual -> out ----
  {
    const int tg4 = (tid >> 4) * 4;
    const int og = (tid & 15) * 4;
    float acc[4][4] = {};
    for (int c8 = 0; c8 < 256; c8 += 8) {
      us8v gr[4];
#pragma unroll
      for (int j = 0; j < 4; ++j)
        gr[j] = *reinterpret_cast<const us8v*>(&g2[(tg4 + j) * 256 + c8]);
#pragma unroll
      for (int cc = 0; cc < 8; ++cc) {
        float wf[4];
        bf4arr(*reinterpret_cast<const ushort4*>(&w2s[(c8 + cc) * 68 + og]), wf);
#pragma unroll
        for (int j = 0; j < 4; ++j) {
          float a = bf2f(gr[j][cc]);
#pragma unroll
          for (int k = 0; k < 4; ++k) acc[j][k] += a * wf[k];
        }
      }
    }
#pragma unroll
    for (int j = 0; j < 4; ++j) {
      const int token = tg4 + j;
      const int gy = ty0 + (token >> 3), gx = tx0 + (token & 7);
      const long idx = ((long)b * NTOK + gy * 384 + gx) * 64 + og;
      float4 xv = *reinterpret_cast<const float4*>(x1 + idx);
      float4 ov;
      ov.x = xv.x + acc[j][0] + b2[og + 0];
      ov.y = xv.y + acc[j][1] + b2[og + 1];
      ov.z = xv.z + acc[j][2] + b2[og + 2];
      ov.w = xv.w + acc[j][3] + b2[og + 3];
      *reinterpret_cast<float4*>(out + idx) = ov;
    }
  }
}

extern "C" void kernel_launch(void* const* d_in, const int* in_sizes, int n_in,
                              void* d_out, int out_size, void* d_ws, size_t ws_size,
                              hipStream_t stream) {
  const float* x     = (const float*)d_in[0];
  const float* n1g   = (const float*)d_in[1];
  const float* n1b   = (const float*)d_in[2];
  const float* wq    = (const float*)d_in[3];
  const float* bq    = (const float*)d_in[4];
  const float* wkv   = (const float*)d_in[5];
  const float* bkv   = (const float*)d_in[6];
  const float* relb  = (const float*)d_in[7];
  const float* wproj = (const float*)d_in[8];
  const float* bproj = (const float*)d_in[9];
  const float* n2g   = (const float*)d_in[10];
  const float* n2b   = (const float*)d_in[11];
  const float* w1    = (const float*)d_in[12];
  const float* b1    = (const float*)d_in[13];
  const float* dwk   = (const float*)d_in[14];
  const float* dwb   = (const float*)d_in[15];
  const float* w2    = (const float*)d_in[16];
  const float* b2    = (const float*)d_in[17];

  float* x1  = (float*)d_ws;   // (B, H*W, C) fp32 = 75.5 MB
  float* outp = (float*)d_out;

  k_attn<<<4608, 256, 0, stream>>>(x, n1g, n1b, wq, bq, wkv, bkv, relb, wproj, bproj, x1);
  k_mlp<<<4608, 256, 0, stream>>>(x1, n2g, n2b, w1, b1, dwk, dwb, w2, b2, outp);
}

// Round 2
// 681.848 us; speedup vs baseline: 2.3223x; 2.3223x over previous
//
#include <hip/hip_runtime.h>
#include <math.h>

typedef unsigned short u16;
typedef __attribute__((ext_vector_type(8))) unsigned short us8;
typedef __attribute__((ext_vector_type(8))) __bf16 bf16x8;
typedef __attribute__((ext_vector_type(4))) float f32x4;

#define MFMA16(a, b, c) __builtin_amdgcn_mfma_f32_16x16x32_bf16((a), (b), (c), 0, 0, 0)

static __device__ __forceinline__ float bf2f(u16 u) {
  union { unsigned int i; float f; } v; v.i = ((unsigned int)u) << 16; return v.f;
}
static __device__ __forceinline__ u16 f2bf(float f) {
  union { float f; unsigned int i; } v; v.f = f;
  unsigned int i = v.i;
  unsigned int r = (i + 0x7FFFu + ((i >> 16) & 1u)) >> 16;
  return (u16)r;
}
static __device__ __forceinline__ bf16x8 ldfrag(const u16* p) {
  us8 v = *reinterpret_cast<const us8*>(p);
  return __builtin_bit_cast(bf16x8, v);
}
static __device__ __forceinline__ float gelu_f(float x) {
  return 0.5f * x * (1.0f + erff(x * 0.70710678118654752f));
}

#define NTOK 147456  // 384*384
#define NWX 48

// ---------------------------------------------------------------------------
// Kernel 1: LN1 + windowed MHSA (MFMA) + proj + residual -> x1
// one block (256 thr, 4 waves) per 8x8 window
// ---------------------------------------------------------------------------
__global__ __launch_bounds__(256) void k_attn(
    const float* __restrict__ x,
    const float* __restrict__ n1g, const float* __restrict__ n1b,
    const float* __restrict__ wq, const float* __restrict__ bq,
    const float* __restrict__ wkv, const float* __restrict__ bkv,
    const float* __restrict__ relb,
    const float* __restrict__ wproj, const float* __restrict__ bproj,
    float* __restrict__ x1)
{
  __shared__ u16 xs[64 * 72];
  __shared__ u16 wT[192 * 72];    // [o][c] transposed q|k|v weights
  __shared__ u16 qsm[64 * 72];
  __shared__ u16 ksm[64 * 72];
  __shared__ u16 vT[64 * 72];     // [ch][token]
  __shared__ u16 Ps[2][64 * 72];  // probs per head
  __shared__ u16 osm[64 * 72];
  __shared__ u16 wpT[64 * 72];
  __shared__ float relbs[450];
  __shared__ float red[2][4][64];

  const int tid = threadIdx.x;
  const int wave = tid >> 6, ln = tid & 63;
  const int blk = blockIdx.x;
  const int b = blk / 2304;
  const int rem = blk - b * 2304;
  const int wy = rem / NWX, wx = rem - wy * NWX;

  // ---- stage transposed bf16 weights ----
  for (int i = tid; i < 4096; i += 256) {
    int c = i >> 6, o = i & 63;
    wT[o * 72 + c] = f2bf(wq[i]);
  }
  for (int i = tid; i < 8192; i += 256) {
    int c = i >> 7, o2 = i & 127;
    wT[(64 + o2) * 72 + c] = f2bf(wkv[i]);   // k rows 64..127, v rows 128..191
  }
  for (int i = tid; i < 4096; i += 256) {
    int c = i >> 6, o = i & 63;
    wpT[o * 72 + c] = f2bf(wproj[i]);
  }
  for (int i = tid; i < 450; i += 256) relbs[i] = relb[i];

  // ---- load window + LN1 -> xs (bf16) ----
  {
    const int t = tid >> 2, g = tid & 3;
    const int gy = wy * 8 + (t >> 3), gx = wx * 8 + (t & 7);
    const long rowbase = ((long)b * NTOK + gy * 384 + gx) * 64;
    float loc[16];
    float s0 = 0.f, s1 = 0.f;
#pragma unroll
    for (int k = 0; k < 16; k += 4) {
      float4 v4 = *reinterpret_cast<const float4*>(x + rowbase + g * 16 + k);
      loc[k] = v4.x; loc[k + 1] = v4.y; loc[k + 2] = v4.z; loc[k + 3] = v4.w;
    }
#pragma unroll
    for (int k = 0; k < 16; ++k) { s0 += loc[k]; s1 += loc[k] * loc[k]; }
    red[0][g][t] = s0; red[1][g][t] = s1;
    __syncthreads();
    float m = (red[0][0][t] + red[0][1][t] + red[0][2][t] + red[0][3][t]) * 0.015625f;
    float var = (red[1][0][t] + red[1][1][t] + red[1][2][t] + red[1][3][t]) * 0.015625f - m * m;
    float rs = rsqrtf(var + 1e-5f);
#pragma unroll
    for (int k = 0; k < 16; ++k) {
      int c = g * 16 + k;
      xs[t * 72 + c] = f2bf((loc[k] - m) * rs * n1g[c] + n1b[c]);
    }
  }
  __syncthreads();

  const int lg = ln >> 4;       // lane group 0..3
  const int lr = ln & 15;       // lane within group

  // ---- QKV: [64 x 64] @ [64 x 192] ----
  for (int t = wave * 12; t < wave * 12 + 12; ++t) {
    const int i0 = (t & 3) * 16, n0 = (t >> 2) * 16;
    f32x4 acc = {};
    bf16x8 a0 = ldfrag(&xs[(i0 + lr) * 72 + lg * 8]);
    bf16x8 a1 = ldfrag(&xs[(i0 + lr) * 72 + 32 + lg * 8]);
    bf16x8 b0 = ldfrag(&wT[(n0 + lr) * 72 + lg * 8]);
    bf16x8 b1 = ldfrag(&wT[(n0 + lr) * 72 + 32 + lg * 8]);
    acc = MFMA16(a0, b0, acc);
    acc = MFMA16(a1, b1, acc);
    const int oc = n0 + lr;
    const float bias = (oc < 64) ? bq[oc] : bkv[oc - 64];
#pragma unroll
    for (int r = 0; r < 4; ++r) {
      const int tok = i0 + lg * 4 + r;
      const float val = acc[r] + bias;
      if (oc < 64)       qsm[tok * 72 + oc] = f2bf(val);
      else if (oc < 128) ksm[tok * 72 + (oc - 64)] = f2bf(val);
      else               vT[(oc - 128) * 72 + tok] = f2bf(val);
    }
  }
  __syncthreads();

  // ---- S = scale*Q@K^T + bias, softmax -> Ps (bf16) ----
  for (int s = wave; s < 8; s += 4) {
    const int h = s >> 2, i0 = (s & 3) * 16, hc = h * 32;
    f32x4 sc[4];
    bf16x8 aq = ldfrag(&qsm[(i0 + lr) * 72 + hc + lg * 8]);
#pragma unroll
    for (int jt = 0; jt < 4; ++jt) {
      bf16x8 bk = ldfrag(&ksm[(jt * 16 + lr) * 72 + hc + lg * 8]);
      f32x4 z = {};
      sc[jt] = MFMA16(aq, bk, z);
    }
    const int rowbase = i0 + lg * 4;
#pragma unroll
    for (int r = 0; r < 4; ++r) {
      const int i = rowbase + r;
      const int iy = i >> 3, ix = i & 7;
      float pv[4];
      float mx = -1e30f;
#pragma unroll
      for (int jt = 0; jt < 4; ++jt) {
        const int j = jt * 16 + lr;
        const int dy = iy - (j >> 3) + 7, dx = ix - (j & 7) + 7;
        pv[jt] = sc[jt][r] * 0.17677669529663687f + relbs[(dy * 15 + dx) * 2 + h];
        mx = fmaxf(mx, pv[jt]);
      }
#pragma unroll
      for (int off = 1; off < 16; off <<= 1) mx = fmaxf(mx, __shfl_xor(mx, off));
      float sum = 0.f;
#pragma unroll
      for (int jt = 0; jt < 4; ++jt) { pv[jt] = __expf(pv[jt] - mx); sum += pv[jt]; }
#pragma unroll
      for (int off = 1; off < 16; off <<= 1) sum += __shfl_xor(sum, off);
      const float inv = 1.f / sum;
#pragma unroll
      for (int jt = 0; jt < 4; ++jt)
        Ps[h][i * 72 + jt * 16 + lr] = f2bf(pv[jt] * inv);
    }
  }
  __syncthreads();

  // ---- O = P @ V ----
  for (int q = 0; q < 4; ++q) {
    const int t = wave * 4 + q;
    const int h = t >> 3, rest = t & 7;
    const int i0 = (rest >> 1) * 16, d0 = (rest & 1) * 16;
    f32x4 acc = {};
#pragma unroll
    for (int ks = 0; ks < 64; ks += 32) {
      bf16x8 ap = ldfrag(&Ps[h][(i0 + lr) * 72 + ks + lg * 8]);
      bf16x8 bv = ldfrag(&vT[(h * 32 + d0 + lr) * 72 + ks + lg * 8]);
      acc = MFMA16(ap, bv, acc);
    }
#pragma unroll
    for (int r = 0; r < 4; ++r)
      osm[(i0 + lg * 4 + r) * 72 + h * 32 + d0 + lr] = f2bf(acc[r]);
  }
  __syncthreads();

  // ---- proj + residual -> x1 ----
  for (int q = 0; q < 4; ++q) {
    const int t = wave * 4 + q;
    const int i0 = (t & 3) * 16, o0 = (t >> 2) * 16;
    f32x4 acc = {};
#pragma unroll
    for (int ks = 0; ks < 64; ks += 32) {
      bf16x8 ao = ldfrag(&osm[(i0 + lr) * 72 + ks + lg * 8]);
      bf16x8 bw = ldfrag(&wpT[(o0 + lr) * 72 + ks + lg * 8]);
      acc = MFMA16(ao, bw, acc);
    }
    const int oc = o0 + lr;
    const float bp = bproj[oc];
#pragma unroll
    for (int r = 0; r < 4; ++r) {
      const int tok = i0 + lg * 4 + r;
      const int gy = wy * 8 + (tok >> 3), gx = wx * 8 + (tok & 7);
      const long idx = ((long)b * NTOK + gy * 384 + gx) * 64 + oc;
      x1[idx] = x[idx] + acc[r] + bp;
    }
  }
}

// ---------------------------------------------------------------------------
// Kernel 2: LN2 + fc1(MFMA) + gelu + dwconv3x3 + gelu + fc2(MFMA) + residual
// one block (512 thr, 8 waves) per 8x8 tile, 10x10 halo
// ---------------------------------------------------------------------------
__global__ __launch_bounds__(512) void k_mlp(
    const float* __restrict__ x1,
    const float* __restrict__ n2g, const float* __restrict__ n2b,
    const float* __restrict__ w1, const float* __restrict__ pb1,
    const float* __restrict__ dwk, const float* __restrict__ dwb,
    const float* __restrict__ w2, const float* __restrict__ pb2,
    float* __restrict__ out)
{
  __shared__ u16 ht[100 * 264];               // gelu(fc1) tile [p][oc]
  __shared__ __align__(16) char pool[67584];
  u16* xs2 = (u16*)pool;                      // [112][72] (rows >=100 unused)
  u16* w1T = (u16*)(pool + 16128);            // [256][72]
  u16* g2  = (u16*)pool;                      // [64][264]
  u16* w2T = (u16*)(pool + 33792);            // [64][264]

  const int tid = threadIdx.x;
  const int wave = tid >> 6, ln = tid & 63;
  const int lg = ln >> 4, lr = ln & 15;
  const int blk = blockIdx.x;
  const int b = blk / 2304;
  const int rem = blk - b * 2304;
  const int ty0 = (rem / NWX) * 8, tx0 = (rem - (rem / NWX) * NWX) * 8;

  // stage w1^T
  for (int i = tid; i < 16384; i += 512) {
    int c = i >> 8, o = i & 255;
    w1T[o * 72 + c] = f2bf(w1[i]);
  }

  // ---- LN2 over 10x10 halo (one wave per token) ----
  {
    const float gg = n2g[ln], bb = n2b[ln];
    for (int it = 0; it < 13; ++it) {
      const int p = it * 8 + wave;
      if (p < 100) {
        const int py = ty0 + p / 10 - 1;
        const int px = tx0 + (p - (p / 10) * 10) - 1;
        float v = 0.f;
        if (py >= 0 && py < 384 && px >= 0 && px < 384) {
          float xv = x1[((long)b * NTOK + py * 384 + px) * 64 + ln];
          float sum = xv, sq = xv * xv;
#pragma unroll
          for (int off = 32; off >= 1; off >>= 1) {
            sum += __shfl_xor(sum, off);
            sq  += __shfl_xor(sq, off);
          }
          float m = sum * 0.015625f;
          float var = sq * 0.015625f - m * m;
          v = (xv - m) * rsqrtf(var + 1e-5f) * gg + bb;
        }
        xs2[p * 72 + ln] = f2bf(v);
      }
    }
  }
  __syncthreads();

  // ---- fc1 + gelu -> ht ----
  for (int t = wave * 14; t < wave * 14 + 14; ++t) {
    const int i0 = (t >> 4) * 16, n0 = (t & 15) * 16;
    f32x4 acc = {};
    bf16x8 a0 = ldfrag(&xs2[(i0 + lr) * 72 + lg * 8]);
    bf16x8 a1 = ldfrag(&xs2[(i0 + lr) * 72 + 32 + lg * 8]);
    bf16x8 b0 = ldfrag(&w1T[(n0 + lr) * 72 + lg * 8]);
    bf16x8 b1 = ldfrag(&w1T[(n0 + lr) * 72 + 32 + lg * 8]);
    acc = MFMA16(a0, b0, acc);
    acc = MFMA16(a1, b1, acc);
    const int oc = n0 + lr;
    const float bias = pb1[oc];
#pragma unroll
    for (int r = 0; r < 4; ++r) {
      const int p = i0 + lg * 4 + r;
      if (p < 100) {
        const int py = ty0 + p / 10 - 1;
        const int px = tx0 + (p - (p / 10) * 10) - 1;
        const bool oob = (py < 0 || py >= 384 || px < 0 || px >= 384);
        ht[p * 264 + oc] = oob ? (u16)0 : f2bf(gelu_f(acc[r] + bias));
      }
    }
  }
  __syncthreads();

  // ---- stage w2^T + depthwise conv 3x3 + gelu -> g2 ----
  for (int i = tid; i < 16384; i += 512) {
    int c = i >> 6, o = i & 63;
    w2T[o * 264 + c] = f2bf(w2[i]);
  }
  {
    const int ch = ln * 4;
    float wk[4][9], bb4[4];
#pragma unroll
    for (int k = 0; k < 4; ++k) {
      bb4[k] = dwb[ch + k];
#pragma unroll
      for (int q = 0; q < 9; ++q) wk[k][q] = dwk[(ch + k) * 9 + q];
    }
    for (int tk = 0; tk < 8; ++tk) {
      const int token = wave * 8 + tk;
      const int ty = token >> 3, tx = token & 7;
      float acc[4] = { bb4[0], bb4[1], bb4[2], bb4[3] };
#pragma unroll
      for (int dy = 0; dy < 3; ++dy)
#pragma unroll
        for (int dx = 0; dx < 3; ++dx) {
          const int p = (ty + dy) * 10 + (tx + dx);
          ushort4 hv = *reinterpret_cast<const ushort4*>(&ht[p * 264 + ch]);
          const int q = dy * 3 + dx;
          acc[0] += bf2f(hv.x) * wk[0][q];
          acc[1] += bf2f(hv.y) * wk[1][q];
          acc[2] += bf2f(hv.z) * wk[2][q];
          acc[3] += bf2f(hv.w) * wk[3][q];
        }
      ushort4 ov;
      ov.x = f2bf(gelu_f(acc[0]));
      ov.y = f2bf(gelu_f(acc[1]));
      ov.z = f2bf(gelu_f(acc[2]));
      ov.w = f2bf(gelu_f(acc[3]));
      *reinterpret_cast<ushort4*>(&g2[token * 264 + ch]) = ov;
    }
  }
  __syncthreads();

  // ---- fc2 + residual -> out ----
  for (int q = 0; q < 2; ++q) {
    const int t = wave * 2 + q;
    const int i0 = (t & 3) * 16, o0 = (t >> 2) * 16;
    f32x4 acc = {};
#pragma unroll
    for (int ks = 0; ks < 256; ks += 32) {
      bf16x8 ag = ldfrag(&g2[(i0 + lr) * 264 + ks + lg * 8]);
      bf16x8 bw = ldfrag(&w2T[(o0 + lr) * 264 + ks + lg * 8]);
      acc = MFMA16(ag, bw, acc);
    }
    const int oc = o0 + lr;
    const float bias = pb2[oc];
#pragma unroll
    for (int r = 0; r < 4; ++r) {
      const int token = i0 + lg * 4 + r;
      const int gy = ty0 + (token >> 3), gx = tx0 + (token & 7);
      const long idx = ((long)b * NTOK + gy * 384 + gx) * 64 + oc;
      out[idx] = x1[idx] + acc[r] + bias;
    }
  }
}

extern "C" void kernel_launch(void* const* d_in, const int* in_sizes, int n_in,
                              void* d_out, int out_size, void* d_ws, size_t ws_size,
                              hipStream_t stream) {
  const float* x     = (const float*)d_in[0];
  const float* n1g   = (const float*)d_in[1];
  const float* n1b   = (const float*)d_in[2];
  const float* wq    = (const float*)d_in[3];
  const float* bq    = (const float*)d_in[4];
  const float* wkv   = (const float*)d_in[5];
  const float* bkv   = (const float*)d_in[6];
  const float* relb  = (const float*)d_in[7];
  const float* wproj = (const float*)d_in[8];
  const float* bproj = (const float*)d_in[9];
  const float* n2g   = (const float*)d_in[10];
  const float* n2b   = (const float*)d_in[11];
  const float* w1    = (const float*)d_in[12];
  const float* b1    = (const float*)d_in[13];
  const float* dwk   = (const float*)d_in[14];
  const float* dwb   = (const float*)d_in[15];
  const float* w2    = (const float*)d_in[16];
  const float* b2    = (const float*)d_in[17];

  float* x1   = (float*)d_ws;
  float* outp = (float*)d_out;

  k_attn<<<4608, 256, 0, stream>>>(x, n1g, n1b, wq, bq, wkv, bkv, relb, wproj, bproj, x1);
  k_mlp<<<4608, 512, 0, stream>>>(x1, n2g, n2b, w1, b1, dwk, dwb, w2, b2, outp);
}

// Round 3
// 528.904 us; speedup vs baseline: 2.9938x; 1.2892x over previous
//
#include <hip/hip_runtime.h>
#include <math.h>

typedef unsigned short u16;
typedef __attribute__((ext_vector_type(8))) unsigned short us8;
typedef __attribute__((ext_vector_type(8))) __bf16 bf16x8;
typedef __attribute__((ext_vector_type(4))) float f32x4;

#define MFMA16(a, b, c) __builtin_amdgcn_mfma_f32_16x16x32_bf16((a), (b), (c), 0, 0, 0)

static __device__ __forceinline__ float bf2f(u16 u) {
  union { unsigned int i; float f; } v; v.i = ((unsigned int)u) << 16; return v.f;
}
static __device__ __forceinline__ u16 f2bf(float f) {
  union { float f; unsigned int i; } v; v.f = f;
  unsigned int i = v.i;
  unsigned int r = (i + 0x7FFFu + ((i >> 16) & 1u)) >> 16;
  return (u16)r;
}
static __device__ __forceinline__ bf16x8 ldfrag(const u16* p) {
  us8 v = *reinterpret_cast<const us8*>(p);
  return __builtin_bit_cast(bf16x8, v);
}
// tanh-based gelu (max err vs erf-gelu ~3e-3, well under threshold)
static __device__ __forceinline__ float gelu_f(float x) {
  float u = 0.7978845608028654f * x * (1.0f + 0.044715f * x * x);
  float au = fabsf(u);
  float e = __expf(-2.0f * au);
  float t = (1.0f - e) / (1.0f + e);
  t = (u >= 0.0f) ? t : -t;
  return 0.5f * x * (1.0f + t);
}

#define NTOK 147456  // 384*384
#define NWX 48

// ---------------------------------------------------------------------------
// Kernel 1: LN1 + windowed MHSA (MFMA) + proj + residual -> x1
// one block = 2 windows, 512 thr (waves 0-3 -> win0, 4-7 -> win1)
// ---------------------------------------------------------------------------
__global__ __launch_bounds__(512, 2) void k_attn(
    const float* __restrict__ x,
    const float* __restrict__ n1g, const float* __restrict__ n1b,
    const float* __restrict__ wq, const float* __restrict__ bq,
    const float* __restrict__ wkv, const float* __restrict__ bkv,
    const float* __restrict__ relb,
    const float* __restrict__ wproj, const float* __restrict__ bproj,
    float* __restrict__ x1)
{
  __shared__ u16 wT[192 * 72];      // q|k|v weights transposed [o][c]
  __shared__ u16 wpT[64 * 72];
  __shared__ float relbs[450];
  __shared__ u16 xsw[2][64 * 72];   // xs, later P (per head)
  __shared__ u16 qsw[2][64 * 72];   // Q, later O
  __shared__ u16 ksw[2][64 * 72];   // K
  __shared__ u16 vTw[2][64 * 72];   // V transposed [ch][token]
  __shared__ float red[2][2][4][64];

  const int tid = threadIdx.x;
  const int w2i = tid >> 8;          // window in block
  const int t8 = tid & 255;
  const int wave = tid >> 6;
  const int ln = tid & 63;
  const int lg = ln >> 4, lr = ln & 15;
  const int wv = wave & 3;           // wave within window

  const int blk = blockIdx.x;        // 2304 blocks (2 windows each)
  const int b = blk / 1152;
  const int rem = blk - b * 1152;
  const int wid = rem * 2 + w2i;
  const int wy = wid / NWX, wx = wid - wy * NWX;

  u16* xs  = xsw[w2i];
  u16* qsm = qsw[w2i];
  u16* ksm = ksw[w2i];
  u16* vT  = vTw[w2i];

  // ---- stage shared weights (bf16, transposed) ----
  for (int i = tid; i < 4096; i += 512) { int c = i >> 6, o = i & 63; wT[o * 72 + c] = f2bf(wq[i]); }
  for (int i = tid; i < 8192; i += 512) { int c = i >> 7, o2 = i & 127; wT[(64 + o2) * 72 + c] = f2bf(wkv[i]); }
  for (int i = tid; i < 4096; i += 512) { int c = i >> 6, o = i & 63; wpT[o * 72 + c] = f2bf(wproj[i]); }
  for (int i = tid; i < 450; i += 512) relbs[i] = relb[i];

  // ---- load window + LN1 -> xs ----
  {
    const int t = t8 >> 2, g = t8 & 3;
    const int gy = wy * 8 + (t >> 3), gx = wx * 8 + (t & 7);
    const long rowbase = ((long)b * NTOK + gy * 384 + gx) * 64;
    float loc[16];
    float s0 = 0.f, s1 = 0.f;
#pragma unroll
    for (int k = 0; k < 16; k += 4) {
      float4 v4 = *reinterpret_cast<const float4*>(x + rowbase + g * 16 + k);
      loc[k] = v4.x; loc[k + 1] = v4.y; loc[k + 2] = v4.z; loc[k + 3] = v4.w;
    }
#pragma unroll
    for (int k = 0; k < 16; ++k) { s0 += loc[k]; s1 += loc[k] * loc[k]; }
    red[w2i][0][g][t] = s0; red[w2i][1][g][t] = s1;
    __syncthreads();
    float m = (red[w2i][0][0][t] + red[w2i][0][1][t] + red[w2i][0][2][t] + red[w2i][0][3][t]) * 0.015625f;
    float var = (red[w2i][1][0][t] + red[w2i][1][1][t] + red[w2i][1][2][t] + red[w2i][1][3][t]) * 0.015625f - m * m;
    float rs = rsqrtf(var + 1e-5f);
#pragma unroll
    for (int k = 0; k < 16; ++k) {
      int c = g * 16 + k;
      xs[t * 72 + c] = f2bf((loc[k] - m) * rs * n1g[c] + n1b[c]);
    }
  }
  __syncthreads();

  // ---- QKV: [64x64] @ [64x192] ; 12 tiles per wave ----
  for (int q = 0; q < 12; ++q) {
    const int t = wv * 12 + q;
    const int i0 = (t & 3) * 16, n0 = (t >> 2) * 16;
    f32x4 acc = {};
    bf16x8 a0 = ldfrag(&xs[(i0 + lr) * 72 + lg * 8]);
    bf16x8 a1 = ldfrag(&xs[(i0 + lr) * 72 + 32 + lg * 8]);
    bf16x8 b0 = ldfrag(&wT[(n0 + lr) * 72 + lg * 8]);
    bf16x8 b1 = ldfrag(&wT[(n0 + lr) * 72 + 32 + lg * 8]);
    acc = MFMA16(a0, b0, acc);
    acc = MFMA16(a1, b1, acc);
    const int oc = n0 + lr;
    const float bias = (oc < 64) ? bq[oc] : bkv[oc - 64];
#pragma unroll
    for (int r = 0; r < 4; ++r) {
      const int tok = i0 + lg * 4 + r;
      const float val = acc[r] + bias;
      if (oc < 64)       qsm[tok * 72 + oc] = f2bf(val);
      else if (oc < 128) ksm[tok * 72 + (oc - 64)] = f2bf(val);
      else               vT[(oc - 128) * 72 + tok] = f2bf(val);
    }
  }
  __syncthreads();

  // ---- per-head: S+softmax -> Ps (xs region), PV -> regs ----
  f32x4 oacc[2][2];
#pragma unroll 1
  for (int h = 0; h < 2; ++h) {
    const int hc = h * 32;
    {
      const int i0 = wv * 16;
      f32x4 sc[4];
      bf16x8 aq = ldfrag(&qsm[(i0 + lr) * 72 + hc + lg * 8]);
#pragma unroll
      for (int jt = 0; jt < 4; ++jt) {
        bf16x8 bk = ldfrag(&ksm[(jt * 16 + lr) * 72 + hc + lg * 8]);
        f32x4 z = {};
        sc[jt] = MFMA16(aq, bk, z);
      }
#pragma unroll
      for (int r = 0; r < 4; ++r) {
        const int i = i0 + lg * 4 + r;
        const int iy = i >> 3, ix = i & 7;
        float pv[4];
        float mx = -1e30f;
#pragma unroll
        for (int jt = 0; jt < 4; ++jt) {
          const int j = jt * 16 + lr;
          const int dy = iy - (j >> 3) + 7, dx = ix - (j & 7) + 7;
          pv[jt] = sc[jt][r] * 0.17677669529663687f + relbs[(dy * 15 + dx) * 2 + h];
          mx = fmaxf(mx, pv[jt]);
        }
#pragma unroll
        for (int off = 1; off < 16; off <<= 1) mx = fmaxf(mx, __shfl_xor(mx, off));
        float sum = 0.f;
#pragma unroll
        for (int jt = 0; jt < 4; ++jt) { pv[jt] = __expf(pv[jt] - mx); sum += pv[jt]; }
#pragma unroll
        for (int off = 1; off < 16; off <<= 1) sum += __shfl_xor(sum, off);
        const float inv = 1.f / sum;
#pragma unroll
        for (int jt = 0; jt < 4; ++jt)
          xs[i * 72 + jt * 16 + lr] = f2bf(pv[jt] * inv);   // Ps
      }
    }
    __syncthreads();
    // PV: 2 tiles per wave (i0 = wv*16, d0 = q*16)
#pragma unroll
    for (int q = 0; q < 2; ++q) {
      const int i0 = wv * 16, d0 = q * 16;
      f32x4 acc = {};
#pragma unroll
      for (int ks = 0; ks < 64; ks += 32) {
        bf16x8 ap = ldfrag(&xs[(i0 + lr) * 72 + ks + lg * 8]);
        bf16x8 bv = ldfrag(&vT[(hc + d0 + lr) * 72 + ks + lg * 8]);
        acc = MFMA16(ap, bv, acc);
      }
      oacc[h][q] = acc;
    }
    __syncthreads();
  }

  // ---- write O (qsm region) ----
#pragma unroll
  for (int h = 0; h < 2; ++h)
#pragma unroll
    for (int q = 0; q < 2; ++q) {
      const int i0 = wv * 16;
      const int ch = h * 32 + q * 16 + lr;
#pragma unroll
      for (int r = 0; r < 4; ++r)
        qsm[(i0 + lg * 4 + r) * 72 + ch] = f2bf(oacc[h][q][r]);
    }
  __syncthreads();

  // ---- proj + residual -> x1 ----
  for (int q = 0; q < 4; ++q) {
    const int t = wv * 4 + q;
    const int i0 = (t & 3) * 16, o0 = (t >> 2) * 16;
    f32x4 acc = {};
#pragma unroll
    for (int ks = 0; ks < 64; ks += 32) {
      bf16x8 ao = ldfrag(&qsm[(i0 + lr) * 72 + ks + lg * 8]);
      bf16x8 bw = ldfrag(&wpT[(o0 + lr) * 72 + ks + lg * 8]);
      acc = MFMA16(ao, bw, acc);
    }
    const int oc = o0 + lr;
    const float bp = bproj[oc];
#pragma unroll
    for (int r = 0; r < 4; ++r) {
      const int tok = i0 + lg * 4 + r;
      const int gy = wy * 8 + (tok >> 3), gx = wx * 8 + (tok & 7);
      const long idx = ((long)b * NTOK + gy * 384 + gx) * 64 + oc;
      x1[idx] = x[idx] + acc[r] + bp;
    }
  }
}

// ---------------------------------------------------------------------------
// Kernel 2: LN2 + fc1 + gelu + dwconv3x3 + gelu + fc2 + residual
// HID chunked by 64: LDS ~57KB -> 2 blocks/CU. 512 thr.
// ---------------------------------------------------------------------------
__global__ __launch_bounds__(512, 4) void k_mlp(
    const float* __restrict__ x1,
    const float* __restrict__ n2g, const float* __restrict__ n2b,
    const float* __restrict__ w1, const float* __restrict__ pb1,
    const float* __restrict__ dwk, const float* __restrict__ dwb,
    const float* __restrict__ w2, const float* __restrict__ pb2,
    float* __restrict__ out)
{
  __shared__ u16 xs2[112 * 72];   // LN2 tile (rows >=100 unused/garbage, gated)
  __shared__ u16 ht[100 * 72];    // gelu(fc1) chunk
  __shared__ u16 g2[64 * 72];     // gelu(dwconv) chunk
  __shared__ u16 w1c[64 * 72];    // w1 chunk  [o][c]
  __shared__ u16 w2c[64 * 72];    // w2 chunk  [oc][c2]

  const int tid = threadIdx.x;
  const int wave = tid >> 6, ln = tid & 63;
  const int lg = ln >> 4, lr = ln & 15;
  const int blk = blockIdx.x;
  const int b = blk / 2304;
  const int rem = blk - b * 2304;
  const int ty0 = (rem / NWX) * 8, tx0 = (rem - (rem / NWX) * NWX) * 8;

  // ---- LN2 over 10x10 halo (one wave per token) ----
  {
    const float gg = n2g[ln], bb = n2b[ln];
    for (int it = 0; it < 13; ++it) {
      const int p = it * 8 + wave;
      if (p < 100) {
        const int py = ty0 + p / 10 - 1;
        const int px = tx0 + (p - (p / 10) * 10) - 1;
        float v = 0.f;
        if (py >= 0 && py < 384 && px >= 0 && px < 384) {
          float xv = x1[((long)b * NTOK + py * 384 + px) * 64 + ln];
          float sum = xv, sq = xv * xv;
#pragma unroll
          for (int off = 32; off >= 1; off >>= 1) {
            sum += __shfl_xor(sum, off);
            sq  += __shfl_xor(sq, off);
          }
          float m = sum * 0.015625f;
          float var = sq * 0.015625f - m * m;
          v = (xv - m) * rsqrtf(var + 1e-5f) * gg + bb;
        }
        xs2[p * 72 + ln] = f2bf(v);
      }
    }
  }

  f32x4 facc[2] = {};   // fc2 accumulators (2 tiles per wave)

#pragma unroll 1
  for (int ch = 0; ch < 4; ++ch) {
    __syncthreads();   // prev-chunk fc2 reads done before restaging
    // stage w1 chunk: w1T_c[o][c] = w1[c][ch*64+o]
    for (int i = tid; i < 4096; i += 512) {
      int c = i >> 6, o = i & 63;
      w1c[o * 72 + c] = f2bf(w1[c * 256 + ch * 64 + o]);
    }
    // stage w2 chunk: w2T_c[oc][c2] = w2[ch*64+c2][oc]
    for (int i = tid; i < 4096; i += 512) {
      int c2 = i >> 6, o = i & 63;
      w2c[o * 72 + c2] = f2bf(w2[(ch * 64 + c2) * 64 + o]);
    }
    __syncthreads();

    // fc1 chunk + gelu -> ht  (28 tiles: 7 row-tiles x 4 col-tiles)
    for (int t = wave; t < 28; t += 8) {
      const int i0 = (t >> 2) * 16, n0 = (t & 3) * 16;
      f32x4 acc = {};
      bf16x8 a0 = ldfrag(&xs2[(i0 + lr) * 72 + lg * 8]);
      bf16x8 a1 = ldfrag(&xs2[(i0 + lr) * 72 + 32 + lg * 8]);
      bf16x8 b0 = ldfrag(&w1c[(n0 + lr) * 72 + lg * 8]);
      bf16x8 b1 = ldfrag(&w1c[(n0 + lr) * 72 + 32 + lg * 8]);
      acc = MFMA16(a0, b0, acc);
      acc = MFMA16(a1, b1, acc);
      const int oc = n0 + lr;
      const float bias = pb1[ch * 64 + oc];
#pragma unroll
      for (int r = 0; r < 4; ++r) {
        const int p = i0 + lg * 4 + r;
        if (p < 100) {
          const int py = ty0 + p / 10 - 1;
          const int px = tx0 + (p - (p / 10) * 10) - 1;
          const bool oob = (py < 0 || py >= 384 || px < 0 || px >= 384);
          ht[p * 72 + oc] = oob ? (u16)0 : f2bf(gelu_f(acc[r] + bias));
        }
      }
    }
    __syncthreads();

    // dwconv 3x3 + gelu -> g2 (thread: channel ln, 8 tokens)
    {
      const int gch = ch * 64 + ln;
      float wk[9];
      const float bb = dwb[gch];
#pragma unroll
      for (int q = 0; q < 9; ++q) wk[q] = dwk[gch * 9 + q];
      for (int tk = 0; tk < 8; ++tk) {
        const int token = wave * 8 + tk;
        const int ty = token >> 3, tx = token & 7;
        float a = bb;
#pragma unroll
        for (int dy = 0; dy < 3; ++dy)
#pragma unroll
          for (int dx = 0; dx < 3; ++dx)
            a += bf2f(ht[((ty + dy) * 10 + (tx + dx)) * 72 + ln]) * wk[dy * 3 + dx];
        g2[token * 72 + ln] = f2bf(gelu_f(a));
      }
    }
    __syncthreads();

    // fc2 partial accumulate (2 tiles per wave, K=64 chunk)
#pragma unroll
    for (int q = 0; q < 2; ++q) {
      const int t = wave * 2 + q;
      const int i0 = (t & 3) * 16, o0 = (t >> 2) * 16;
      bf16x8 ag0 = ldfrag(&g2[(i0 + lr) * 72 + lg * 8]);
      bf16x8 ag1 = ldfrag(&g2[(i0 + lr) * 72 + 32 + lg * 8]);
      bf16x8 bw0 = ldfrag(&w2c[(o0 + lr) * 72 + lg * 8]);
      bf16x8 bw1 = ldfrag(&w2c[(o0 + lr) * 72 + 32 + lg * 8]);
      facc[q] = MFMA16(ag0, bw0, facc[q]);
      facc[q] = MFMA16(ag1, bw1, facc[q]);
    }
  }

  // ---- epilogue: + bias + residual -> out ----
#pragma unroll
  for (int q = 0; q < 2; ++q) {
    const int t = wave * 2 + q;
    const int i0 = (t & 3) * 16, o0 = (t >> 2) * 16;
    const int oc = o0 + lr;
    const float bias = pb2[oc];
#pragma unroll
    for (int r = 0; r < 4; ++r) {
      const int token = i0 + lg * 4 + r;
      const int gy = ty0 + (token >> 3), gx = tx0 + (token & 7);
      const long idx = ((long)b * NTOK + gy * 384 + gx) * 64 + oc;
      out[idx] = x1[idx] + facc[q][r] + bias;
    }
  }
}

extern "C" void kernel_launch(void* const* d_in, const int* in_sizes, int n_in,
                              void* d_out, int out_size, void* d_ws, size_t ws_size,
                              hipStream_t stream) {
  const float* x     = (const float*)d_in[0];
  const float* n1g   = (const float*)d_in[1];
  const float* n1b   = (const float*)d_in[2];
  const float* wq    = (const float*)d_in[3];
  const float* bq    = (const float*)d_in[4];
  const float* wkv   = (const float*)d_in[5];
  const float* bkv   = (const float*)d_in[6];
  const float* relb  = (const float*)d_in[7];
  const float* wproj = (const float*)d_in[8];
  const float* bproj = (const float*)d_in[9];
  const float* n2g   = (const float*)d_in[10];
  const float* n2b   = (const float*)d_in[11];
  const float* w1    = (const float*)d_in[12];
  const float* b1    = (const float*)d_in[13];
  const float* dwk   = (const float*)d_in[14];
  const float* dwb   = (const float*)d_in[15];
  const float* w2    = (const float*)d_in[16];
  const float* b2    = (const float*)d_in[17];

  float* x1   = (float*)d_ws;
  float* outp = (float*)d_out;

  k_attn<<<2304, 512, 0, stream>>>(x, n1g, n1b, wq, bq, wkv, bkv, relb, wproj, bproj, x1);
  k_mlp<<<4608, 512, 0, stream>>>(x1, n2g, n2b, w1, b1, dwk, dwb, w2, b2, outp);
}

// Round 4
// 359.753 us; speedup vs baseline: 4.4015x; 1.4702x over previous
//
#include <hip/hip_runtime.h>
#include <math.h>

typedef unsigned short u16;
typedef __attribute__((ext_vector_type(8))) unsigned short us8;
typedef __attribute__((ext_vector_type(8))) __bf16 bf16x8;
typedef __attribute__((ext_vector_type(4))) float f32x4;

#define MFMA16(a, b, c) __builtin_amdgcn_mfma_f32_16x16x32_bf16((a), (b), (c), 0, 0, 0)

static __device__ __forceinline__ float bf2f(u16 u) {
  union { unsigned int i; float f; } v; v.i = ((unsigned int)u) << 16; return v.f;
}
static __device__ __forceinline__ u16 f2bf(float f) {
  union { float f; unsigned int i; } v; v.f = f;
  unsigned int i = v.i;
  unsigned int r = (i + 0x7FFFu + ((i >> 16) & 1u)) >> 16;
  return (u16)r;
}
static __device__ __forceinline__ bf16x8 ldfrag(const u16* p) {
  us8 v = *reinterpret_cast<const us8*>(p);
  return __builtin_bit_cast(bf16x8, v);
}
// sigmoid-gelu: x * sigmoid(1.702x). |err| vs erf-gelu <= ~0.02, OK for threshold.
static __device__ __forceinline__ float gelu_s(float x) {
  return x * __builtin_amdgcn_rcpf(1.0f + __expf(-1.702f * x));
}

#define NTOK 147456  // 384*384
#define NWX 48

// ---------------------------------------------------------------------------
// Prep: transpose weights to bf16 [o][c], expand rel bias table
// ---------------------------------------------------------------------------
__global__ __launch_bounds__(256) void k_prep(
    const float* __restrict__ wq, const float* __restrict__ wkv,
    const float* __restrict__ wproj, const float* __restrict__ w1,
    const float* __restrict__ w2, const float* __restrict__ relb,
    u16* __restrict__ wqkvT, u16* __restrict__ wpT,
    u16* __restrict__ w1T, u16* __restrict__ w2T, float* __restrict__ biasx)
{
  const int idx = blockIdx.x * 256 + threadIdx.x;
  const int NT = 64 * 256;
  for (int i = idx; i < 12288; i += NT) {
    int o = i >> 6, c = i & 63;
    wqkvT[i] = f2bf(o < 64 ? wq[c * 64 + o] : wkv[c * 128 + (o - 64)]);
  }
  for (int i = idx; i < 4096; i += NT) {
    int o = i >> 6, c = i & 63;
    wpT[i] = f2bf(wproj[c * 64 + o]);
  }
  for (int i = idx; i < 16384; i += NT) {
    int o = i >> 6, c = i & 63;
    w1T[i] = f2bf(w1[c * 256 + o]);
  }
  for (int i = idx; i < 16384; i += NT) {
    int o = i >> 8, c2 = i & 255;
    w2T[i] = f2bf(w2[c2 * 64 + o]);
  }
  for (int i = idx; i < 8192; i += NT) {
    int h = i >> 12, r = i & 4095, ii = r >> 6, j = r & 63;
    int dy = (ii >> 3) - (j >> 3) + 7, dx = (ii & 7) - (j & 7) + 7;
    biasx[i] = relb[(dy * 15 + dx) * 2 + h];
  }
}

// ---------------------------------------------------------------------------
// Kernel 1: LN1 + windowed MHSA + proj + residual -> x1, plus LN2 stats -> mrs
// one block = 2 windows, 512 thr
// ---------------------------------------------------------------------------
__global__ __launch_bounds__(512, 2) void k_attn(
    const float* __restrict__ x,
    const float* __restrict__ n1g, const float* __restrict__ n1b,
    const u16* __restrict__ wqkvT, const float* __restrict__ bq,
    const float* __restrict__ bkv, const float* __restrict__ biasx,
    const u16* __restrict__ wpT, const float* __restrict__ bproj,
    float2* __restrict__ mrs, float* __restrict__ x1)
{
  __shared__ u16 xsw[2][64 * 72];   // LN1 out, later P
  __shared__ u16 qsw[2][64 * 72];   // Q, later O
  __shared__ u16 ksw[2][64 * 72];   // K
  __shared__ u16 vTw[2][64 * 72];   // V transposed [ch][token]
  __shared__ float red[2][2][4][64];

  const int tid = threadIdx.x;
  const int w2i = tid >> 8;
  const int t8 = tid & 255;
  const int wave = tid >> 6;
  const int ln = tid & 63;
  const int lg = ln >> 4, lr = ln & 15;
  const int wv = wave & 3;

  const int blk = blockIdx.x;
  const int b = blk / 1152;
  const int rem = blk - b * 1152;
  const int wid = rem * 2 + w2i;
  const int wy = wid / NWX, wx = wid - wy * NWX;

  u16* xs  = xsw[w2i];
  u16* qsm = qsw[w2i];
  u16* ksm = ksw[w2i];
  u16* vT  = vTw[w2i];

  // ---- load window + LN1 -> xs ----
  {
    const int t = t8 >> 2, g = t8 & 3;
    const int gy = wy * 8 + (t >> 3), gx = wx * 8 + (t & 7);
    const long rowbase = ((long)b * NTOK + gy * 384 + gx) * 64;
    float loc[16];
    float s0 = 0.f, s1 = 0.f;
#pragma unroll
    for (int k = 0; k < 16; k += 4) {
      float4 v4 = *reinterpret_cast<const float4*>(x + rowbase + g * 16 + k);
      loc[k] = v4.x; loc[k + 1] = v4.y; loc[k + 2] = v4.z; loc[k + 3] = v4.w;
    }
#pragma unroll
    for (int k = 0; k < 16; ++k) { s0 += loc[k]; s1 += loc[k] * loc[k]; }
    red[w2i][0][g][t] = s0; red[w2i][1][g][t] = s1;
    __syncthreads();
    float m = (red[w2i][0][0][t] + red[w2i][0][1][t] + red[w2i][0][2][t] + red[w2i][0][3][t]) * 0.015625f;
    float var = (red[w2i][1][0][t] + red[w2i][1][1][t] + red[w2i][1][2][t] + red[w2i][1][3][t]) * 0.015625f - m * m;
    float rs = rsqrtf(var + 1e-5f);
#pragma unroll
    for (int k = 0; k < 16; ++k) {
      int c = g * 16 + k;
      xs[t * 72 + c] = f2bf((loc[k] - m) * rs * n1g[c] + n1b[c]);
    }
  }
  __syncthreads();

  // ---- QKV: [64x64] @ [64x192], B-frags from global ----
  for (int q = 0; q < 12; ++q) {
    const int t = wv * 12 + q;
    const int i0 = (t & 3) * 16, n0 = (t >> 2) * 16;
    f32x4 acc = {};
    bf16x8 a0 = ldfrag(&xs[(i0 + lr) * 72 + lg * 8]);
    bf16x8 a1 = ldfrag(&xs[(i0 + lr) * 72 + 32 + lg * 8]);
    bf16x8 b0 = ldfrag(&wqkvT[(n0 + lr) * 64 + lg * 8]);
    bf16x8 b1 = ldfrag(&wqkvT[(n0 + lr) * 64 + 32 + lg * 8]);
    acc = MFMA16(a0, b0, acc);
    acc = MFMA16(a1, b1, acc);
    const int oc = n0 + lr;
    const float bias = (oc < 64) ? bq[oc] : bkv[oc - 64];
#pragma unroll
    for (int r = 0; r < 4; ++r) {
      const int tok = i0 + lg * 4 + r;
      const float val = acc[r] + bias;
      if (oc < 64)       qsm[tok * 72 + oc] = f2bf(val);
      else if (oc < 128) ksm[tok * 72 + (oc - 64)] = f2bf(val);
      else               vT[(oc - 128) * 72 + tok] = f2bf(val);
    }
  }
  __syncthreads();

  // ---- per-head: S + softmax -> Ps (xs region), PV -> regs ----
  f32x4 oacc[2][2];
#pragma unroll 1
  for (int h = 0; h < 2; ++h) {
    const int hc = h * 32;
    {
      const int i0 = wv * 16;
      f32x4 sc[4];
      bf16x8 aq = ldfrag(&qsm[(i0 + lr) * 72 + hc + lg * 8]);
#pragma unroll
      for (int jt = 0; jt < 4; ++jt) {
        bf16x8 bk = ldfrag(&ksm[(jt * 16 + lr) * 72 + hc + lg * 8]);
        f32x4 z = {};
        sc[jt] = MFMA16(aq, bk, z);
      }
#pragma unroll
      for (int r = 0; r < 4; ++r) {
        const int i = i0 + lg * 4 + r;
        const float* brow = biasx + h * 4096 + i * 64;
        float pv[4];
        float mx = -1e30f;
#pragma unroll
        for (int jt = 0; jt < 4; ++jt) {
          pv[jt] = fmaf(sc[jt][r], 0.17677669529663687f, brow[jt * 16 + lr]);
          mx = fmaxf(mx, pv[jt]);
        }
#pragma unroll
        for (int off = 1; off < 16; off <<= 1) mx = fmaxf(mx, __shfl_xor(mx, off));
        float sum = 0.f;
#pragma unroll
        for (int jt = 0; jt < 4; ++jt) { pv[jt] = __expf(pv[jt] - mx); sum += pv[jt]; }
#pragma unroll
        for (int off = 1; off < 16; off <<= 1) sum += __shfl_xor(sum, off);
        const float inv = __builtin_amdgcn_rcpf(sum);
#pragma unroll
        for (int jt = 0; jt < 4; ++jt)
          xs[i * 72 + jt * 16 + lr] = f2bf(pv[jt] * inv);   // P
      }
    }
    __syncthreads();
#pragma unroll
    for (int q = 0; q < 2; ++q) {
      const int i0 = wv * 16, d0 = q * 16;
      f32x4 acc = {};
#pragma unroll
      for (int ks = 0; ks < 64; ks += 32) {
        bf16x8 ap = ldfrag(&xs[(i0 + lr) * 72 + ks + lg * 8]);
        bf16x8 bv = ldfrag(&vT[(hc + d0 + lr) * 72 + ks + lg * 8]);
        acc = MFMA16(ap, bv, acc);
      }
      oacc[h][q] = acc;
    }
    __syncthreads();
  }

  // ---- write O (qsm region) ----
#pragma unroll
  for (int h = 0; h < 2; ++h)
#pragma unroll
    for (int q = 0; q < 2; ++q) {
      const int i0 = wv * 16;
      const int ch = h * 32 + q * 16 + lr;
#pragma unroll
      for (int r = 0; r < 4; ++r)
        qsm[(i0 + lg * 4 + r) * 72 + ch] = f2bf(oacc[h][q][r]);
    }
  __syncthreads();

  // ---- proj + residual -> x1, plus LN2 stats -> mrs ----
  {
    const int i0 = wv * 16;      // this wave owns tokens i0..i0+15 entirely
    float s[4] = {}, sq[4] = {};
#pragma unroll
    for (int q = 0; q < 4; ++q) {
      const int o0 = q * 16;
      f32x4 acc = {};
#pragma unroll
      for (int ks = 0; ks < 64; ks += 32) {
        bf16x8 ao = ldfrag(&qsm[(i0 + lr) * 72 + ks + lg * 8]);
        bf16x8 bw = ldfrag(&wpT[(o0 + lr) * 64 + ks + lg * 8]);
        acc = MFMA16(ao, bw, acc);
      }
      const int oc = o0 + lr;
      const float bp = bproj[oc];
#pragma unroll
      for (int r = 0; r < 4; ++r) {
        const int tok = i0 + lg * 4 + r;
        const int gy = wy * 8 + (tok >> 3), gx = wx * 8 + (tok & 7);
        const long idx = ((long)b * NTOK + gy * 384 + gx) * 64 + oc;
        const float v = x[idx] + acc[r] + bp;
        x1[idx] = v;
        s[r] += v; sq[r] += v * v;
      }
    }
#pragma unroll
    for (int r = 0; r < 4; ++r) {
      float ss = s[r], qq = sq[r];
#pragma unroll
      for (int off = 1; off < 16; off <<= 1) {
        ss += __shfl_xor(ss, off);
        qq += __shfl_xor(qq, off);
      }
      if (lr == 0) {
        const float m = ss * 0.015625f;
        const float var = qq * 0.015625f - m * m;
        const int tok = i0 + lg * 4 + r;
        const int gy = wy * 8 + (tok >> 3), gx = wx * 8 + (tok & 7);
        mrs[(long)b * NTOK + gy * 384 + gx] = make_float2(m, rsqrtf(var + 1e-5f));
      }
    }
  }
}

// ---------------------------------------------------------------------------
// Kernel 2: LN2-apply + fc1 + gelu + dwconv3x3 + gelu + fc2 + residual
// HID chunked by 64; weights from global; 512 thr, ~58KB LDS -> 2 blocks/CU
// ---------------------------------------------------------------------------
__global__ __launch_bounds__(512, 4) void k_mlp(
    const float* __restrict__ x1, const float2* __restrict__ mrs,
    const float* __restrict__ n2g, const float* __restrict__ n2b,
    const u16* __restrict__ w1T, const float* __restrict__ pb1,
    const float* __restrict__ dwk, const float* __restrict__ dwb,
    const u16* __restrict__ w2T, const float* __restrict__ pb2,
    float* __restrict__ out)
{
  __shared__ u16 xln[112 * 72];    // LN2'd halo tile (bf16), rows 100..111 zero
  __shared__ float htf[112 * 76];  // gelu(fc1) chunk (f32), stride 76 vs conflicts
  __shared__ u16 g2[64 * 72];      // gelu(dwconv) chunk (bf16)
  __shared__ float flag[112];      // 1.0 if halo pos in-image else 0.0

  const int tid = threadIdx.x;
  const int wave = tid >> 6, ln = tid & 63;
  const int lg = ln >> 4, lr = ln & 15;
  const int blk = blockIdx.x;
  const int b = blk / 2304;
  const int rem = blk - b * 2304;
  const int ty0 = (rem / NWX) * 8, tx0 = (rem - (rem / NWX) * NWX) * 8;

  if (tid < 112) {
    float f = 0.f;
    if (tid < 100) {
      const int py = ty0 + tid / 10 - 1, px = tx0 + tid % 10 - 1;
      if (py >= 0 && py < 384 && px >= 0 && px < 384) f = 1.f;
    }
    flag[tid] = f;
  }

  // ---- LN2 apply over halo (one wave per row) ----
  {
    const float gg = n2g[ln], bb = n2b[ln];
    for (int p = wave; p < 112; p += 8) {
      u16 o = 0;
      if (p < 100) {
        const int py = ty0 + p / 10 - 1, px = tx0 + p % 10 - 1;
        if (py >= 0 && py < 384 && px >= 0 && px < 384) {
          const long tok = (long)b * NTOK + py * 384 + px;
          const float2 mr = mrs[tok];
          const float v = x1[tok * 64 + ln];
          o = f2bf((v - mr.x) * mr.y * gg + bb);
        }
      }
      xln[p * 72 + ln] = o;
    }
  }

  f32x4 facc[2] = {};

#pragma unroll 1
  for (int ch = 0; ch < 4; ++ch) {
    __syncthreads();   // xln ready (ch=0) / prev g2 reads done

    // ---- fc1 chunk + gelu -> htf (f32) ----
    for (int t = wave; t < 28; t += 8) {
      const int i0 = (t >> 2) * 16, n0 = (t & 3) * 16;
      f32x4 acc = {};
      bf16x8 a0 = ldfrag(&xln[(i0 + lr) * 72 + lg * 8]);
      bf16x8 a1 = ldfrag(&xln[(i0 + lr) * 72 + 32 + lg * 8]);
      bf16x8 b0 = ldfrag(&w1T[(ch * 64 + n0 + lr) * 64 + lg * 8]);
      bf16x8 b1 = ldfrag(&w1T[(ch * 64 + n0 + lr) * 64 + 32 + lg * 8]);
      acc = MFMA16(a0, b0, acc);
      acc = MFMA16(a1, b1, acc);
      const int oc = n0 + lr;
      const float bias = pb1[ch * 64 + oc];
#pragma unroll
      for (int r = 0; r < 4; ++r) {
        const int p = i0 + lg * 4 + r;
        htf[p * 76 + oc] = gelu_s(acc[r] + bias) * flag[p];
      }
    }
    __syncthreads();

    // ---- dwconv 3x3 + gelu -> g2 (wave = token row, lane = channel) ----
    {
      const int gch = ch * 64 + ln;
      float wk[9];
      const float db = dwb[gch];
#pragma unroll
      for (int q = 0; q < 9; ++q) wk[q] = dwk[gch * 9 + q];
      float ca[3], cb[3], cc[3];
#pragma unroll
      for (int dr = 0; dr < 3; ++dr) {
        ca[dr] = htf[((wave + dr) * 10 + 0) * 76 + ln];
        cb[dr] = htf[((wave + dr) * 10 + 1) * 76 + ln];
      }
#pragma unroll
      for (int tx = 0; tx < 8; ++tx) {
        float a = db;
#pragma unroll
        for (int dr = 0; dr < 3; ++dr) {
          cc[dr] = htf[((wave + dr) * 10 + tx + 2) * 76 + ln];
          a += ca[dr] * wk[dr * 3] + cb[dr] * wk[dr * 3 + 1] + cc[dr] * wk[dr * 3 + 2];
        }
        g2[(wave * 8 + tx) * 72 + ln] = f2bf(gelu_s(a));
#pragma unroll
        for (int dr = 0; dr < 3; ++dr) { ca[dr] = cb[dr]; cb[dr] = cc[dr]; }
      }
    }
    __syncthreads();

    // ---- fc2 partial accumulate ----
#pragma unroll
    for (int q = 0; q < 2; ++q) {
      const int t = wave * 2 + q;
      const int i0 = (t & 3) * 16, o0 = (t >> 2) * 16;
      bf16x8 ag0 = ldfrag(&g2[(i0 + lr) * 72 + lg * 8]);
      bf16x8 ag1 = ldfrag(&g2[(i0 + lr) * 72 + 32 + lg * 8]);
      bf16x8 bw0 = ldfrag(&w2T[(o0 + lr) * 256 + ch * 64 + lg * 8]);
      bf16x8 bw1 = ldfrag(&w2T[(o0 + lr) * 256 + ch * 64 + 32 + lg * 8]);
      facc[q] = MFMA16(ag0, bw0, facc[q]);
      facc[q] = MFMA16(ag1, bw1, facc[q]);
    }
  }

  // ---- epilogue: + bias + residual -> out ----
#pragma unroll
  for (int q = 0; q < 2; ++q) {
    const int t = wave * 2 + q;
    const int i0 = (t & 3) * 16, o0 = (t >> 2) * 16;
    const int oc = o0 + lr;
    const float bias = pb2[oc];
#pragma unroll
    for (int r = 0; r < 4; ++r) {
      const int token = i0 + lg * 4 + r;
      const int gy = ty0 + (token >> 3), gx = tx0 + (token & 7);
      const long idx = ((long)b * NTOK + gy * 384 + gx) * 64 + oc;
      out[idx] = x1[idx] + facc[q][r] + bias;
    }
  }
}

extern "C" void kernel_launch(void* const* d_in, const int* in_sizes, int n_in,
                              void* d_out, int out_size, void* d_ws, size_t ws_size,
                              hipStream_t stream) {
  const float* x     = (const float*)d_in[0];
  const float* n1g   = (const float*)d_in[1];
  const float* n1b   = (const float*)d_in[2];
  const float* wq    = (const float*)d_in[3];
  const float* bq    = (const float*)d_in[4];
  const float* wkv   = (const float*)d_in[5];
  const float* bkv   = (const float*)d_in[6];
  const float* relb  = (const float*)d_in[7];
  const float* wproj = (const float*)d_in[8];
  const float* bproj = (const float*)d_in[9];
  const float* n2g   = (const float*)d_in[10];
  const float* n2b   = (const float*)d_in[11];
  const float* w1    = (const float*)d_in[12];
  const float* b1    = (const float*)d_in[13];
  const float* dwk   = (const float*)d_in[14];
  const float* dwb   = (const float*)d_in[15];
  const float* w2    = (const float*)d_in[16];
  const float* b2    = (const float*)d_in[17];

  char* ws = (char*)d_ws;
  u16*    wqkvT = (u16*)ws;                    //  24576 B
  u16*    wpT   = (u16*)(ws + 24576);          //   8192 B
  u16*    w1T   = (u16*)(ws + 32768);          //  32768 B
  u16*    w2T   = (u16*)(ws + 65536);          //  32768 B
  float*  biasx = (float*)(ws + 98304);        //  32768 B
  float2* mrs   = (float2*)(ws + 131072);      // 2359296 B
  float*  x1    = (float*)(ws + 2490368);      // 75497472 B (total ~78 MB)
  float*  outp  = (float*)d_out;

  k_prep<<<64, 256, 0, stream>>>(wq, wkv, wproj, w1, w2, relb, wqkvT, wpT, w1T, w2T, biasx);
  k_attn<<<2304, 512, 0, stream>>>(x, n1g, n1b, wqkvT, bq, bkv, biasx, wpT, bproj, mrs, x1);
  k_mlp<<<4608, 512, 0, stream>>>(x1, mrs, n2g, n2b, w1T, b1, dwk, dwb, w2T, b2, outp);
}

// Round 5
// 340.388 us; speedup vs baseline: 4.6519x; 1.0569x over previous
//
#include <hip/hip_runtime.h>
#include <hip/hip_bf16.h>
#include <math.h>

typedef unsigned short u16;
typedef __attribute__((ext_vector_type(8))) unsigned short us8;
typedef __attribute__((ext_vector_type(8))) __bf16 bf16x8;
typedef __attribute__((ext_vector_type(4))) float f32x4;

#define MFMA16(a, b, c) __builtin_amdgcn_mfma_f32_16x16x32_bf16((a), (b), (c), 0, 0, 0)

static __device__ __forceinline__ float bf2f(u16 u) {
  union { unsigned int i; float f; } v; v.i = ((unsigned int)u) << 16; return v.f;
}
// hardware RNE convert (compiler emits v_cvt_pk_bf16_f32 for pairs)
static __device__ __forceinline__ u16 f2bf(float f) {
  __hip_bfloat16 h = __float2bfloat16(f);
  return *reinterpret_cast<u16*>(&h);
}
static __device__ __forceinline__ bf16x8 ldfrag(const u16* p) {
  us8 v = *reinterpret_cast<const us8*>(p);
  return __builtin_bit_cast(bf16x8, v);
}
// sigmoid-gelu: x * sigmoid(1.702x). |err| vs erf-gelu <= ~0.02, OK for threshold.
static __device__ __forceinline__ float gelu_s(float x) {
  return x * __builtin_amdgcn_rcpf(1.0f + __expf(-1.702f * x));
}

#define NTOK 147456  // 384*384
#define NWX 48

// ---------------------------------------------------------------------------
// Prep: transpose weights to bf16 [o][c], expand rel bias table
// ---------------------------------------------------------------------------
__global__ __launch_bounds__(256) void k_prep(
    const float* __restrict__ wq, const float* __restrict__ wkv,
    const float* __restrict__ wproj, const float* __restrict__ w1,
    const float* __restrict__ w2, const float* __restrict__ relb,
    u16* __restrict__ wqkvT, u16* __restrict__ wpT,
    u16* __restrict__ w1T, u16* __restrict__ w2T, float* __restrict__ biasx)
{
  const int idx = blockIdx.x * 256 + threadIdx.x;
  const int NT = 64 * 256;
  for (int i = idx; i < 12288; i += NT) {
    int o = i >> 6, c = i & 63;
    wqkvT[i] = f2bf(o < 64 ? wq[c * 64 + o] : wkv[c * 128 + (o - 64)]);
  }
  for (int i = idx; i < 4096; i += NT) {
    int o = i >> 6, c = i & 63;
    wpT[i] = f2bf(wproj[c * 64 + o]);
  }
  for (int i = idx; i < 16384; i += NT) {
    int o = i >> 6, c = i & 63;
    w1T[i] = f2bf(w1[c * 256 + o]);
  }
  for (int i = idx; i < 16384; i += NT) {
    int o = i >> 8, c2 = i & 255;
    w2T[i] = f2bf(w2[c2 * 64 + o]);
  }
  for (int i = idx; i < 8192; i += NT) {
    int h = i >> 12, r = i & 4095, ii = r >> 6, j = r & 63;
    int dy = (ii >> 3) - (j >> 3) + 7, dx = (ii & 7) - (j & 7) + 7;
    biasx[i] = relb[(dy * 15 + dx) * 2 + h];
  }
}

// ---------------------------------------------------------------------------
// Kernel 1: LN1 + windowed MHSA + proj + residual -> x1, plus LN2 stats -> mrs
// one block = 2 windows, 512 thr
// ---------------------------------------------------------------------------
__global__ __launch_bounds__(512, 2) void k_attn(
    const float* __restrict__ x,
    const float* __restrict__ n1g, const float* __restrict__ n1b,
    const u16* __restrict__ wqkvT, const float* __restrict__ bq,
    const float* __restrict__ bkv, const float* __restrict__ biasx,
    const u16* __restrict__ wpT, const float* __restrict__ bproj,
    float2* __restrict__ mrs, float* __restrict__ x1)
{
  __shared__ u16 xsw[2][64 * 72];   // LN1 out, later P
  __shared__ u16 qsw[2][64 * 72];   // Q, later O
  __shared__ u16 ksw[2][64 * 72];   // K
  __shared__ u16 vTw[2][64 * 72];   // V transposed [ch][token]
  __shared__ float red[2][2][4][64];

  const int tid = threadIdx.x;
  const int w2i = tid >> 8;
  const int t8 = tid & 255;
  const int wave = tid >> 6;
  const int ln = tid & 63;
  const int lg = ln >> 4, lr = ln & 15;
  const int wv = wave & 3;

  const int blk = blockIdx.x;
  const int b = blk / 1152;
  const int rem = blk - b * 1152;
  const int wid = rem * 2 + w2i;
  const int wy = wid / NWX, wx = wid - wy * NWX;

  u16* xs  = xsw[w2i];
  u16* qsm = qsw[w2i];
  u16* ksm = ksw[w2i];
  u16* vT  = vTw[w2i];

  // ---- load window + LN1 -> xs ----
  {
    const int t = t8 >> 2, g = t8 & 3;
    const int gy = wy * 8 + (t >> 3), gx = wx * 8 + (t & 7);
    const long rowbase = ((long)b * NTOK + gy * 384 + gx) * 64;
    float loc[16];
    float s0 = 0.f, s1 = 0.f;
#pragma unroll
    for (int k = 0; k < 16; k += 4) {
      float4 v4 = *reinterpret_cast<const float4*>(x + rowbase + g * 16 + k);
      loc[k] = v4.x; loc[k + 1] = v4.y; loc[k + 2] = v4.z; loc[k + 3] = v4.w;
    }
#pragma unroll
    for (int k = 0; k < 16; ++k) { s0 += loc[k]; s1 += loc[k] * loc[k]; }
    red[w2i][0][g][t] = s0; red[w2i][1][g][t] = s1;
    __syncthreads();
    float m = (red[w2i][0][0][t] + red[w2i][0][1][t] + red[w2i][0][2][t] + red[w2i][0][3][t]) * 0.015625f;
    float var = (red[w2i][1][0][t] + red[w2i][1][1][t] + red[w2i][1][2][t] + red[w2i][1][3][t]) * 0.015625f - m * m;
    float rs = rsqrtf(var + 1e-5f);
#pragma unroll
    for (int k = 0; k < 16; ++k) {
      int c = g * 16 + k;
      xs[t * 72 + c] = f2bf((loc[k] - m) * rs * n1g[c] + n1b[c]);
    }
  }
  __syncthreads();

  // ---- QKV: [64x64] @ [64x192], B-frags from global ----
  for (int q = 0; q < 12; ++q) {
    const int t = wv * 12 + q;
    const int i0 = (t & 3) * 16, n0 = (t >> 2) * 16;
    f32x4 acc = {};
    bf16x8 a0 = ldfrag(&xs[(i0 + lr) * 72 + lg * 8]);
    bf16x8 a1 = ldfrag(&xs[(i0 + lr) * 72 + 32 + lg * 8]);
    bf16x8 b0 = ldfrag(&wqkvT[(n0 + lr) * 64 + lg * 8]);
    bf16x8 b1 = ldfrag(&wqkvT[(n0 + lr) * 64 + 32 + lg * 8]);
    acc = MFMA16(a0, b0, acc);
    acc = MFMA16(a1, b1, acc);
    const int oc = n0 + lr;
    const float bias = (oc < 64) ? bq[oc] : bkv[oc - 64];
#pragma unroll
    for (int r = 0; r < 4; ++r) {
      const int tok = i0 + lg * 4 + r;
      const float val = acc[r] + bias;
      if (oc < 64)       qsm[tok * 72 + oc] = f2bf(val);
      else if (oc < 128) ksm[tok * 72 + (oc - 64)] = f2bf(val);
      else               vT[(oc - 128) * 72 + tok] = f2bf(val);
    }
  }
  __syncthreads();

  // ---- per-head: S + softmax -> Ps (xs region), PV -> regs ----
  f32x4 oacc[2][2];
#pragma unroll 1
  for (int h = 0; h < 2; ++h) {
    const int hc = h * 32;
    {
      const int i0 = wv * 16;
      f32x4 sc[4];
      bf16x8 aq = ldfrag(&qsm[(i0 + lr) * 72 + hc + lg * 8]);
#pragma unroll
      for (int jt = 0; jt < 4; ++jt) {
        bf16x8 bk = ldfrag(&ksm[(jt * 16 + lr) * 72 + hc + lg * 8]);
        f32x4 z = {};
        sc[jt] = MFMA16(aq, bk, z);
      }
#pragma unroll
      for (int r = 0; r < 4; ++r) {
        const int i = i0 + lg * 4 + r;
        const float* brow = biasx + h * 4096 + i * 64;
        float pv[4];
        float mx = -1e30f;
#pragma unroll
        for (int jt = 0; jt < 4; ++jt) {
          pv[jt] = fmaf(sc[jt][r], 0.17677669529663687f, brow[jt * 16 + lr]);
          mx = fmaxf(mx, pv[jt]);
        }
#pragma unroll
        for (int off = 1; off < 16; off <<= 1) mx = fmaxf(mx, __shfl_xor(mx, off));
        float sum = 0.f;
#pragma unroll
        for (int jt = 0; jt < 4; ++jt) { pv[jt] = __expf(pv[jt] - mx); sum += pv[jt]; }
#pragma unroll
        for (int off = 1; off < 16; off <<= 1) sum += __shfl_xor(sum, off);
        const float inv = __builtin_amdgcn_rcpf(sum);
#pragma unroll
        for (int jt = 0; jt < 4; ++jt)
          xs[i * 72 + jt * 16 + lr] = f2bf(pv[jt] * inv);   // P
      }
    }
    __syncthreads();
#pragma unroll
    for (int q = 0; q < 2; ++q) {
      const int i0 = wv * 16, d0 = q * 16;
      f32x4 acc = {};
#pragma unroll
      for (int ks = 0; ks < 64; ks += 32) {
        bf16x8 ap = ldfrag(&xs[(i0 + lr) * 72 + ks + lg * 8]);
        bf16x8 bv = ldfrag(&vT[(hc + d0 + lr) * 72 + ks + lg * 8]);
        acc = MFMA16(ap, bv, acc);
      }
      oacc[h][q] = acc;
    }
    __syncthreads();
  }

  // ---- write O (qsm region) ----
#pragma unroll
  for (int h = 0; h < 2; ++h)
#pragma unroll
    for (int q = 0; q < 2; ++q) {
      const int i0 = wv * 16;
      const int ch = h * 32 + q * 16 + lr;
#pragma unroll
      for (int r = 0; r < 4; ++r)
        qsm[(i0 + lg * 4 + r) * 72 + ch] = f2bf(oacc[h][q][r]);
    }
  __syncthreads();

  // ---- proj + residual -> x1, plus LN2 stats -> mrs ----
  {
    const int i0 = wv * 16;      // this wave owns tokens i0..i0+15 entirely
    float s[4] = {}, sq[4] = {};
#pragma unroll
    for (int q = 0; q < 4; ++q) {
      const int o0 = q * 16;
      f32x4 acc = {};
#pragma unroll
      for (int ks = 0; ks < 64; ks += 32) {
        bf16x8 ao = ldfrag(&qsm[(i0 + lr) * 72 + ks + lg * 8]);
        bf16x8 bw = ldfrag(&wpT[(o0 + lr) * 64 + ks + lg * 8]);
        acc = MFMA16(ao, bw, acc);
      }
      const int oc = o0 + lr;
      const float bp = bproj[oc];
#pragma unroll
      for (int r = 0; r < 4; ++r) {
        const int tok = i0 + lg * 4 + r;
        const int gy = wy * 8 + (tok >> 3), gx = wx * 8 + (tok & 7);
        const long idx = ((long)b * NTOK + gy * 384 + gx) * 64 + oc;
        const float v = x[idx] + acc[r] + bp;
        x1[idx] = v;
        s[r] += v; sq[r] += v * v;
      }
    }
#pragma unroll
    for (int r = 0; r < 4; ++r) {
      float ss = s[r], qq = sq[r];
#pragma unroll
      for (int off = 1; off < 16; off <<= 1) {
        ss += __shfl_xor(ss, off);
        qq += __shfl_xor(qq, off);
      }
      if (lr == 0) {
        const float m = ss * 0.015625f;
        const float var = qq * 0.015625f - m * m;
        const int tok = i0 + lg * 4 + r;
        const int gy = wy * 8 + (tok >> 3), gx = wx * 8 + (tok & 7);
        mrs[(long)b * NTOK + gy * 384 + gx] = make_float2(m, rsqrtf(var + 1e-5f));
      }
    }
  }
}

// ---------------------------------------------------------------------------
// Kernel 2: LN2-apply + fc1 + gelu + dwconv3x3 + gelu + fc2 + residual
// HID chunked by 64; weights from global; 512 thr, 40.6KB LDS -> 4 blocks/CU
// ---------------------------------------------------------------------------
__global__ __launch_bounds__(512, 8) void k_mlp(
    const float* __restrict__ x1, const float2* __restrict__ mrs,
    const float* __restrict__ n2g, const float* __restrict__ n2b,
    const u16* __restrict__ w1T, const float* __restrict__ pb1,
    const float* __restrict__ dwk, const float* __restrict__ dwb,
    const u16* __restrict__ w2T, const float* __restrict__ pb2,
    float* __restrict__ out)
{
  __shared__ u16 xln[112 * 72];    // LN2'd halo tile (bf16), rows 100..111 zero
  __shared__ u16 htb[100 * 74];    // gelu(fc1) chunk (bf16), stride 74
  __shared__ u16 g2[64 * 72];      // gelu(dwconv) chunk (bf16)
  __shared__ float flag[112];      // 1.0 if halo pos in-image else 0.0

  const int tid = threadIdx.x;
  const int wave = tid >> 6, ln = tid & 63;
  const int lg = ln >> 4, lr = ln & 15;
  const int blk = blockIdx.x;
  const int b = blk / 2304;
  const int rem = blk - b * 2304;
  const int ty0 = (rem / NWX) * 8, tx0 = (rem - (rem / NWX) * NWX) * 8;

  if (tid < 112) {
    float f = 0.f;
    if (tid < 100) {
      const int py = ty0 + tid / 10 - 1, px = tx0 + tid % 10 - 1;
      if (py >= 0 && py < 384 && px >= 0 && px < 384) f = 1.f;
    }
    flag[tid] = f;
  }

  // ---- LN2 apply over halo (one wave per row) ----
  {
    const float gg = n2g[ln], bb = n2b[ln];
    for (int p = wave; p < 112; p += 8) {
      u16 o = 0;
      if (p < 100) {
        const int py = ty0 + p / 10 - 1, px = tx0 + p % 10 - 1;
        if (py >= 0 && py < 384 && px >= 0 && px < 384) {
          const long tok = (long)b * NTOK + py * 384 + px;
          const float2 mr = mrs[tok];
          const float v = x1[tok * 64 + ln];
          o = f2bf((v - mr.x) * mr.y * gg + bb);
        }
      }
      xln[p * 72 + ln] = o;
    }
  }

  f32x4 facc[2] = {};

#pragma unroll 1
  for (int ch = 0; ch < 4; ++ch) {
    __syncthreads();   // xln ready (ch=0) / prev g2 reads done

    // ---- fc1 chunk + gelu -> htb (bf16) ----
    for (int t = wave; t < 28; t += 8) {
      const int i0 = (t >> 2) * 16, n0 = (t & 3) * 16;
      f32x4 acc = {};
      bf16x8 a0 = ldfrag(&xln[(i0 + lr) * 72 + lg * 8]);
      bf16x8 a1 = ldfrag(&xln[(i0 + lr) * 72 + 32 + lg * 8]);
      bf16x8 b0 = ldfrag(&w1T[(ch * 64 + n0 + lr) * 64 + lg * 8]);
      bf16x8 b1 = ldfrag(&w1T[(ch * 64 + n0 + lr) * 64 + 32 + lg * 8]);
      acc = MFMA16(a0, b0, acc);
      acc = MFMA16(a1, b1, acc);
      const int oc = n0 + lr;
      const float bias = pb1[ch * 64 + oc];
#pragma unroll
      for (int r = 0; r < 4; ++r) {
        const int p = i0 + lg * 4 + r;
        if (p < 100)
          htb[p * 74 + oc] = f2bf(gelu_s(acc[r] + bias) * flag[p]);
      }
    }
    __syncthreads();

    // ---- dwconv 3x3 + gelu -> g2 (wave = token row, lane = channel) ----
    {
      const int gch = ch * 64 + ln;
      float wk[9];
      const float db = dwb[gch];
#pragma unroll
      for (int q = 0; q < 9; ++q) wk[q] = dwk[gch * 9 + q];
      float ca[3], cb[3], cc[3];
#pragma unroll
      for (int dr = 0; dr < 3; ++dr) {
        ca[dr] = bf2f(htb[((wave + dr) * 10 + 0) * 74 + ln]);
        cb[dr] = bf2f(htb[((wave + dr) * 10 + 1) * 74 + ln]);
      }
#pragma unroll
      for (int tx = 0; tx < 8; ++tx) {
        float a = db;
#pragma unroll
        for (int dr = 0; dr < 3; ++dr) {
          cc[dr] = bf2f(htb[((wave + dr) * 10 + tx + 2) * 74 + ln]);
          a += ca[dr] * wk[dr * 3] + cb[dr] * wk[dr * 3 + 1] + cc[dr] * wk[dr * 3 + 2];
        }
        g2[(wave * 8 + tx) * 72 + ln] = f2bf(gelu_s(a));
#pragma unroll
        for (int dr = 0; dr < 3; ++dr) { ca[dr] = cb[dr]; cb[dr] = cc[dr]; }
      }
    }
    __syncthreads();

    // ---- fc2 partial accumulate ----
#pragma unroll
    for (int q = 0; q < 2; ++q) {
      const int t = wave * 2 + q;
      const int i0 = (t & 3) * 16, o0 = (t >> 2) * 16;
      bf16x8 ag0 = ldfrag(&g2[(i0 + lr) * 72 + lg * 8]);
      bf16x8 ag1 = ldfrag(&g2[(i0 + lr) * 72 + 32 + lg * 8]);
      bf16x8 bw0 = ldfrag(&w2T[(o0 + lr) * 256 + ch * 64 + lg * 8]);
      bf16x8 bw1 = ldfrag(&w2T[(o0 + lr) * 256 + ch * 64 + 32 + lg * 8]);
      facc[q] = MFMA16(ag0, bw0, facc[q]);
      facc[q] = MFMA16(ag1, bw1, facc[q]);
    }
  }

  // ---- epilogue: + bias + residual -> out ----
#pragma unroll
  for (int q = 0; q < 2; ++q) {
    const int t = wave * 2 + q;
    const int i0 = (t & 3) * 16, o0 = (t >> 2) * 16;
    const int oc = o0 + lr;
    const float bias = pb2[oc];
#pragma unroll
    for (int r = 0; r < 4; ++r) {
      const int token = i0 + lg * 4 + r;
      const int gy = ty0 + (token >> 3), gx = tx0 + (token & 7);
      const long idx = ((long)b * NTOK + gy * 384 + gx) * 64 + oc;
      out[idx] = x1[idx] + facc[q][r] + bias;
    }
  }
}

extern "C" void kernel_launch(void* const* d_in, const int* in_sizes, int n_in,
                              void* d_out, int out_size, void* d_ws, size_t ws_size,
                              hipStream_t stream) {
  const float* x     = (const float*)d_in[0];
  const float* n1g   = (const float*)d_in[1];
  const float* n1b   = (const float*)d_in[2];
  const float* wq    = (const float*)d_in[3];
  const float* bq    = (const float*)d_in[4];
  const float* wkv   = (const float*)d_in[5];
  const float* bkv   = (const float*)d_in[6];
  const float* relb  = (const float*)d_in[7];
  const float* wproj = (const float*)d_in[8];
  const float* bproj = (const float*)d_in[9];
  const float* n2g   = (const float*)d_in[10];
  const float* n2b   = (const float*)d_in[11];
  const float* w1    = (const float*)d_in[12];
  const float* b1    = (const float*)d_in[13];
  const float* dwk   = (const float*)d_in[14];
  const float* dwb   = (const float*)d_in[15];
  const float* w2    = (const float*)d_in[16];
  const float* b2    = (const float*)d_in[17];

  char* ws = (char*)d_ws;
  u16*    wqkvT = (u16*)ws;                    //  24576 B
  u16*    wpT   = (u16*)(ws + 24576);          //   8192 B
  u16*    w1T   = (u16*)(ws + 32768);          //  32768 B
  u16*    w2T   = (u16*)(ws + 65536);          //  32768 B
  float*  biasx = (float*)(ws + 98304);        //  32768 B
  float2* mrs   = (float2*)(ws + 131072);      // 2359296 B
  float*  x1    = (float*)(ws + 2490368);      // 75497472 B (total ~78 MB)
  float*  outp  = (float*)d_out;

  k_prep<<<64, 256, 0, stream>>>(wq, wkv, wproj, w1, w2, relb, wqkvT, wpT, w1T, w2T, biasx);
  k_attn<<<2304, 512, 0, stream>>>(x, n1g, n1b, wqkvT, bq, bkv, biasx, wpT, bproj, mrs, x1);
  k_mlp<<<4608, 512, 0, stream>>>(x1, mrs, n2g, n2b, w1T, b1, dwk, dwb, w2T, b2, outp);
}

// Round 6
// 331.823 us; speedup vs baseline: 4.7720x; 1.0258x over previous
//
#include <hip/hip_runtime.h>
#include <hip/hip_bf16.h>
#include <math.h>

typedef unsigned short u16;
typedef unsigned int u32;
typedef __attribute__((ext_vector_type(8))) unsigned short us8;
typedef __attribute__((ext_vector_type(8))) __bf16 bf16x8;
typedef __attribute__((ext_vector_type(4))) float f32x4;

#define MFMA16(a, b, c) __builtin_amdgcn_mfma_f32_16x16x32_bf16((a), (b), (c), 0, 0, 0)

static __device__ __forceinline__ float bf2f(u16 u) {
  union { u32 i; float f; } v; v.i = ((u32)u) << 16; return v.f;
}
static __device__ __forceinline__ u16 f2bf(float f) {
  __hip_bfloat16 h = __float2bfloat16(f);
  return *reinterpret_cast<u16*>(&h);
}
static __device__ __forceinline__ u32 pk2bf(float lo, float hi) {
  return ((u32)f2bf(hi) << 16) | (u32)f2bf(lo);
}
static __device__ __forceinline__ float lo16(u32 v) {
  union { u32 i; float f; } u; u.i = v << 16; return u.f;
}
static __device__ __forceinline__ float hi16(u32 v) {
  union { u32 i; float f; } u; u.i = v & 0xFFFF0000u; return u.f;
}
static __device__ __forceinline__ bf16x8 ldfrag(const u16* p) {
  us8 v = *reinterpret_cast<const us8*>(p);
  return __builtin_bit_cast(bf16x8, v);
}
// sigmoid-gelu: x * sigmoid(1.702x)
static __device__ __forceinline__ float gelu_s(float x) {
  return x * __builtin_amdgcn_rcpf(1.0f + __expf(-1.702f * x));
}

#define NTOK 147456  // 384*384
#define NWX 48

// ---------------------------------------------------------------------------
// Prep: transpose weights to bf16 [o][c], expand rel bias table
// ---------------------------------------------------------------------------
__global__ __launch_bounds__(256) void k_prep(
    const float* __restrict__ wq, const float* __restrict__ wkv,
    const float* __restrict__ wproj, const float* __restrict__ w1,
    const float* __restrict__ w2, const float* __restrict__ relb,
    u16* __restrict__ wqkvT, u16* __restrict__ wpT,
    u16* __restrict__ w1T, u16* __restrict__ w2T, float* __restrict__ biasx)
{
  const int idx = blockIdx.x * 256 + threadIdx.x;
  const int NT = 64 * 256;
  for (int i = idx; i < 12288; i += NT) {
    int o = i >> 6, c = i & 63;
    wqkvT[i] = f2bf(o < 64 ? wq[c * 64 + o] : wkv[c * 128 + (o - 64)]);
  }
  for (int i = idx; i < 4096; i += NT) {
    int o = i >> 6, c = i & 63;
    wpT[i] = f2bf(wproj[c * 64 + o]);
  }
  for (int i = idx; i < 16384; i += NT) {
    int o = i >> 6, c = i & 63;
    w1T[i] = f2bf(w1[c * 256 + o]);
  }
  for (int i = idx; i < 16384; i += NT) {
    int o = i >> 8, c2 = i & 255;
    w2T[i] = f2bf(w2[c2 * 64 + o]);
  }
  for (int i = idx; i < 8192; i += NT) {
    int h = i >> 12, r = i & 4095, ii = r >> 6, j = r & 63;
    int dy = (ii >> 3) - (j >> 3) + 7, dx = (ii & 7) - (j & 7) + 7;
    biasx[i] = relb[(dy * 15 + dx) * 2 + h];
  }
}

// ---------------------------------------------------------------------------
// Kernel 1: LN1 + windowed MHSA + proj + residual -> x1, plus LN2 stats -> mrs
// one block = 2 windows, 512 thr; LDS 73728 B -> 2 blocks/CU
// ---------------------------------------------------------------------------
__global__ __launch_bounds__(512, 4) void k_attn(
    const float* __restrict__ x,
    const float* __restrict__ n1g, const float* __restrict__ n1b,
    const u16* __restrict__ wqkvT, const float* __restrict__ bq,
    const float* __restrict__ bkv, const float* __restrict__ biasx,
    const u16* __restrict__ wpT, const float* __restrict__ bproj,
    float2* __restrict__ mrs, float* __restrict__ x1)
{
  __shared__ u16 xsw[2][64 * 72];   // LN1 out, later P
  __shared__ u16 qsw[2][64 * 72];   // Q, later O
  __shared__ u16 ksw[2][64 * 72];   // K
  __shared__ u16 vTw[2][64 * 72];   // V transposed [ch][token]

  const int tid = threadIdx.x;
  const int w2i = tid >> 8;
  const int t8 = tid & 255;
  const int ln = tid & 63;
  const int lg = ln >> 4, lr = ln & 15;
  const int wv = (tid >> 6) & 3;

  const int blk = blockIdx.x;
  const int b = blk / 1152;
  const int rem = blk - b * 1152;
  const int wid = rem * 2 + w2i;
  const int wy = wid / NWX, wx = wid - wy * NWX;

  u16* xs  = xsw[w2i];
  u16* qsm = qsw[w2i];
  u16* ksm = ksw[w2i];
  u16* vT  = vTw[w2i];

  // ---- load window + LN1 -> xs (4 adjacent lanes own one token) ----
  {
    const int t = t8 >> 2, g = t8 & 3;
    const int gy = wy * 8 + (t >> 3), gx = wx * 8 + (t & 7);
    const long rowbase = ((long)b * NTOK + gy * 384 + gx) * 64;
    float loc[16];
    float s0 = 0.f, s1 = 0.f;
#pragma unroll
    for (int k = 0; k < 16; k += 4) {
      float4 v4 = *reinterpret_cast<const float4*>(x + rowbase + g * 16 + k);
      loc[k] = v4.x; loc[k + 1] = v4.y; loc[k + 2] = v4.z; loc[k + 3] = v4.w;
    }
#pragma unroll
    for (int k = 0; k < 16; ++k) { s0 += loc[k]; s1 += loc[k] * loc[k]; }
    s0 += __shfl_xor(s0, 1); s0 += __shfl_xor(s0, 2);
    s1 += __shfl_xor(s1, 1); s1 += __shfl_xor(s1, 2);
    const float m = s0 * 0.015625f;
    const float var = s1 * 0.015625f - m * m;
    const float rs = rsqrtf(var + 1e-5f);
#pragma unroll
    for (int k = 0; k < 16; ++k) {
      int c = g * 16 + k;
      xs[t * 72 + c] = f2bf((loc[k] - m) * rs * n1g[c] + n1b[c]);
    }
  }
  __syncthreads();

  // ---- QKV: [64x64] @ [64x192], B-frags from global ----
  for (int q = 0; q < 12; ++q) {
    const int t = wv * 12 + q;
    const int i0 = (t & 3) * 16, n0 = (t >> 2) * 16;
    f32x4 acc = {};
    bf16x8 a0 = ldfrag(&xs[(i0 + lr) * 72 + lg * 8]);
    bf16x8 a1 = ldfrag(&xs[(i0 + lr) * 72 + 32 + lg * 8]);
    bf16x8 b0 = ldfrag(&wqkvT[(n0 + lr) * 64 + lg * 8]);
    bf16x8 b1 = ldfrag(&wqkvT[(n0 + lr) * 64 + 32 + lg * 8]);
    acc = MFMA16(a0, b0, acc);
    acc = MFMA16(a1, b1, acc);
    const int oc = n0 + lr;
    const float bias = (oc < 64) ? bq[oc] : bkv[oc - 64];
#pragma unroll
    for (int r = 0; r < 4; ++r) {
      const int tok = i0 + lg * 4 + r;
      const float val = acc[r] + bias;
      if (oc < 64)       qsm[tok * 72 + oc] = f2bf(val);
      else if (oc < 128) ksm[tok * 72 + (oc - 64)] = f2bf(val);
      else               vT[(oc - 128) * 72 + tok] = f2bf(val);
    }
  }
  __syncthreads();

  // ---- per-head: S + softmax -> P (xs region), PV -> regs ----
  f32x4 oacc[2][2];
#pragma unroll 1
  for (int h = 0; h < 2; ++h) {
    const int hc = h * 32;
    {
      const int i0 = wv * 16;
      f32x4 sc[4];
      bf16x8 aq = ldfrag(&qsm[(i0 + lr) * 72 + hc + lg * 8]);
#pragma unroll
      for (int jt = 0; jt < 4; ++jt) {
        bf16x8 bk = ldfrag(&ksm[(jt * 16 + lr) * 72 + hc + lg * 8]);
        f32x4 z = {};
        sc[jt] = MFMA16(aq, bk, z);
      }
#pragma unroll
      for (int r = 0; r < 4; ++r) {
        const int i = i0 + lg * 4 + r;
        const float* brow = biasx + h * 4096 + i * 64;
        float pv[4];
        float mx = -1e30f;
#pragma unroll
        for (int jt = 0; jt < 4; ++jt) {
          pv[jt] = fmaf(sc[jt][r], 0.17677669529663687f, brow[jt * 16 + lr]);
          mx = fmaxf(mx, pv[jt]);
        }
#pragma unroll
        for (int off = 1; off < 16; off <<= 1) mx = fmaxf(mx, __shfl_xor(mx, off));
        float sum = 0.f;
#pragma unroll
        for (int jt = 0; jt < 4; ++jt) { pv[jt] = __expf(pv[jt] - mx); sum += pv[jt]; }
#pragma unroll
        for (int off = 1; off < 16; off <<= 1) sum += __shfl_xor(sum, off);
        const float inv = __builtin_amdgcn_rcpf(sum);
#pragma unroll
        for (int jt = 0; jt < 4; ++jt)
          xs[i * 72 + jt * 16 + lr] = f2bf(pv[jt] * inv);   // P
      }
    }
    __syncthreads();
#pragma unroll
    for (int q = 0; q < 2; ++q) {
      const int i0 = wv * 16, d0 = q * 16;
      f32x4 acc = {};
#pragma unroll
      for (int ks = 0; ks < 64; ks += 32) {
        bf16x8 ap = ldfrag(&xs[(i0 + lr) * 72 + ks + lg * 8]);
        bf16x8 bv = ldfrag(&vT[(hc + d0 + lr) * 72 + ks + lg * 8]);
        acc = MFMA16(ap, bv, acc);
      }
      oacc[h][q] = acc;
    }
    __syncthreads();
  }

  // ---- write O (qsm region) ----
#pragma unroll
  for (int h = 0; h < 2; ++h)
#pragma unroll
    for (int q = 0; q < 2; ++q) {
      const int i0 = wv * 16;
      const int ch = h * 32 + q * 16 + lr;
#pragma unroll
      for (int r = 0; r < 4; ++r)
        qsm[(i0 + lg * 4 + r) * 72 + ch] = f2bf(oacc[h][q][r]);
    }
  __syncthreads();

  // ---- proj + residual -> x1, plus LN2 stats -> mrs ----
  {
    const int i0 = wv * 16;      // this wave owns tokens i0..i0+15 entirely
    float s[4] = {}, sq[4] = {};
#pragma unroll
    for (int q = 0; q < 4; ++q) {
      const int o0 = q * 16;
      f32x4 acc = {};
#pragma unroll
      for (int ks = 0; ks < 64; ks += 32) {
        bf16x8 ao = ldfrag(&qsm[(i0 + lr) * 72 + ks + lg * 8]);
        bf16x8 bw = ldfrag(&wpT[(o0 + lr) * 64 + ks + lg * 8]);
        acc = MFMA16(ao, bw, acc);
      }
      const int oc = o0 + lr;
      const float bp = bproj[oc];
#pragma unroll
      for (int r = 0; r < 4; ++r) {
        const int tok = i0 + lg * 4 + r;
        const int gy = wy * 8 + (tok >> 3), gx = wx * 8 + (tok & 7);
        const long idx = ((long)b * NTOK + gy * 384 + gx) * 64 + oc;
        const float v = x[idx] + acc[r] + bp;
        x1[idx] = v;
        s[r] += v; sq[r] += v * v;
      }
    }
#pragma unroll
    for (int r = 0; r < 4; ++r) {
      float ss = s[r], qq = sq[r];
#pragma unroll
      for (int off = 1; off < 16; off <<= 1) {
        ss += __shfl_xor(ss, off);
        qq += __shfl_xor(qq, off);
      }
      if (lr == 0) {
        const float m = ss * 0.015625f;
        const float var = qq * 0.015625f - m * m;
        const int tok = i0 + lg * 4 + r;
        const int gy = wy * 8 + (tok >> 3), gx = wx * 8 + (tok & 7);
        mrs[(long)b * NTOK + gy * 384 + gx] = make_float2(m, rsqrtf(var + 1e-5f));
      }
    }
  }
}

// ---------------------------------------------------------------------------
// Kernel 2: LN2-apply + fc1 + gelu + dwconv3x3 + gelu + fc2 + residual
// HID chunked by 64; htbT transposed+packed; 38.8KB LDS -> 4 blocks/CU
// ---------------------------------------------------------------------------
__global__ __launch_bounds__(512, 8) void k_mlp(
    const float* __restrict__ x1, const float2* __restrict__ mrs,
    const float* __restrict__ n2g, const float* __restrict__ n2b,
    const u16* __restrict__ w1T, const float* __restrict__ pb1,
    const float* __restrict__ dwk, const float* __restrict__ dwb,
    const u16* __restrict__ w2T, const float* __restrict__ pb2,
    float* __restrict__ out)
{
  __shared__ u16 xln[112 * 72];    // LN2'd halo tile (bf16), rows 100..111 zero
  __shared__ u16 htbT[64 * 102];   // gelu(fc1) chunk, TRANSPOSED [ch][pos]
  __shared__ u16 g2[64 * 72];      // gelu(dwconv) chunk (bf16) [token][ch]
  __shared__ float flag[112];      // 1.0 if halo pos in-image else 0.0

  const int tid = threadIdx.x;
  const int wave = tid >> 6, ln = tid & 63;
  const int lg = ln >> 4, lr = ln & 15;
  const int blk = blockIdx.x;
  const int b = blk / 2304;
  const int rem = blk - b * 2304;
  const int ty0 = (rem / NWX) * 8, tx0 = (rem - (rem / NWX) * NWX) * 8;

  if (tid < 112) {
    float f = 0.f;
    if (tid < 100) {
      const int py = ty0 + tid / 10 - 1, px = tx0 + tid % 10 - 1;
      if (py >= 0 && py < 384 && px >= 0 && px < 384) f = 1.f;
    }
    flag[tid] = f;
  }

  // ---- LN2 apply over halo (one wave per row) ----
  {
    const float gg = n2g[ln], bb = n2b[ln];
    for (int p = wave; p < 112; p += 8) {
      u16 o = 0;
      if (p < 100) {
        const int py = ty0 + p / 10 - 1, px = tx0 + p % 10 - 1;
        if (py >= 0 && py < 384 && px >= 0 && px < 384) {
          const long tok = (long)b * NTOK + py * 384 + px;
          const float2 mr = mrs[tok];
          const float v = x1[tok * 64 + ln];
          o = f2bf((v - mr.x) * mr.y * gg + bb);
        }
      }
      xln[p * 72 + ln] = o;
    }
  }

  f32x4 facc[2] = {};

#pragma unroll 1
  for (int ch = 0; ch < 4; ++ch) {
    __syncthreads();   // xln ready (ch=0) / prev g2 reads done

    // ---- fc1 chunk + gelu -> htbT (packed pairs, 2x ds_write_b32) ----
    for (int t = wave; t < 28; t += 8) {
      const int i0 = (t >> 2) * 16, n0 = (t & 3) * 16;
      f32x4 acc = {};
      bf16x8 a0 = ldfrag(&xln[(i0 + lr) * 72 + lg * 8]);
      bf16x8 a1 = ldfrag(&xln[(i0 + lr) * 72 + 32 + lg * 8]);
      bf16x8 b0 = ldfrag(&w1T[(ch * 64 + n0 + lr) * 64 + lg * 8]);
      bf16x8 b1 = ldfrag(&w1T[(ch * 64 + n0 + lr) * 64 + 32 + lg * 8]);
      acc = MFMA16(a0, b0, acc);
      acc = MFMA16(a1, b1, acc);
      const int oc = n0 + lr;
      const float bias = pb1[ch * 64 + oc];
      const int p0 = i0 + lg * 4;
      if (p0 < 100) {
        float g0 = gelu_s(acc[0] + bias) * flag[p0 + 0];
        float g1 = gelu_s(acc[1] + bias) * flag[p0 + 1];
        float g2v = gelu_s(acc[2] + bias) * flag[p0 + 2];
        float g3 = gelu_s(acc[3] + bias) * flag[p0 + 3];
        u32* dst = reinterpret_cast<u32*>(&htbT[oc * 102 + p0]);
        dst[0] = pk2bf(g0, g1);
        dst[1] = pk2bf(g2v, g3);
      }
    }
    __syncthreads();

    // ---- dwconv 3x3 + gelu -> g2 (wave = token row, lane = channel) ----
    {
      const int gch = ch * 64 + ln;
      float wk[9];
      const float db = dwb[gch];
#pragma unroll
      for (int q = 0; q < 9; ++q) wk[q] = dwk[gch * 9 + q];
      const u16* rowbase = &htbT[ln * 102];
      const u32* r0 = reinterpret_cast<const u32*>(rowbase + (wave + 0) * 10);
      const u32* r1 = reinterpret_cast<const u32*>(rowbase + (wave + 1) * 10);
      const u32* r2 = reinterpret_cast<const u32*>(rowbase + (wave + 2) * 10);
      u32 v;
      float a0,b0,c0,d0, a1,b1,c1,d1, a2,b2,c2,d2;
      v = r0[0]; a0 = lo16(v); b0 = hi16(v);
      v = r0[1]; c0 = lo16(v); d0 = hi16(v);
      v = r1[0]; a1 = lo16(v); b1 = hi16(v);
      v = r1[1]; c1 = lo16(v); d1 = hi16(v);
      v = r2[0]; a2 = lo16(v); b2 = hi16(v);
      v = r2[1]; c2 = lo16(v); d2 = hi16(v);
#pragma unroll
      for (int s = 0; s < 4; ++s) {
        float e0 = db + a0 * wk[0] + b0 * wk[1] + c0 * wk[2]
                      + a1 * wk[3] + b1 * wk[4] + c1 * wk[5]
                      + a2 * wk[6] + b2 * wk[7] + c2 * wk[8];
        float e1 = db + b0 * wk[0] + c0 * wk[1] + d0 * wk[2]
                      + b1 * wk[3] + c1 * wk[4] + d1 * wk[5]
                      + b2 * wk[6] + c2 * wk[7] + d2 * wk[8];
        g2[(wave * 8 + 2 * s) * 72 + ln]     = f2bf(gelu_s(e0));
        g2[(wave * 8 + 2 * s + 1) * 72 + ln] = f2bf(gelu_s(e1));
        if (s < 3) {
          v = r0[s + 2]; a0 = c0; b0 = d0; c0 = lo16(v); d0 = hi16(v);
          v = r1[s + 2]; a1 = c1; b1 = d1; c1 = lo16(v); d1 = hi16(v);
          v = r2[s + 2]; a2 = c2; b2 = d2; c2 = lo16(v); d2 = hi16(v);
        }
      }
    }
    __syncthreads();

    // ---- fc2 partial accumulate ----
#pragma unroll
    for (int q = 0; q < 2; ++q) {
      const int t = wave * 2 + q;
      const int i0 = (t & 3) * 16, o0 = (t >> 2) * 16;
      bf16x8 ag0 = ldfrag(&g2[(i0 + lr) * 72 + lg * 8]);
      bf16x8 ag1 = ldfrag(&g2[(i0 + lr) * 72 + 32 + lg * 8]);
      bf16x8 bw0 = ldfrag(&w2T[(o0 + lr) * 256 + ch * 64 + lg * 8]);
      bf16x8 bw1 = ldfrag(&w2T[(o0 + lr) * 256 + ch * 64 + 32 + lg * 8]);
      facc[q] = MFMA16(ag0, bw0, facc[q]);
      facc[q] = MFMA16(ag1, bw1, facc[q]);
    }
  }

  // ---- epilogue: + bias + residual -> out ----
#pragma unroll
  for (int q = 0; q < 2; ++q) {
    const int t = wave * 2 + q;
    const int i0 = (t & 3) * 16, o0 = (t >> 2) * 16;
    const int oc = o0 + lr;
    const float bias = pb2[oc];
#pragma unroll
    for (int r = 0; r < 4; ++r) {
      const int token = i0 + lg * 4 + r;
      const int gy = ty0 + (token >> 3), gx = tx0 + (token & 7);
      const long idx = ((long)b * NTOK + gy * 384 + gx) * 64 + oc;
      out[idx] = x1[idx] + facc[q][r] + bias;
    }
  }
}

extern "C" void kernel_launch(void* const* d_in, const int* in_sizes, int n_in,
                              void* d_out, int out_size, void* d_ws, size_t ws_size,
                              hipStream_t stream) {
  const float* x     = (const float*)d_in[0];
  const float* n1g   = (const float*)d_in[1];
  const float* n1b   = (const float*)d_in[2];
  const float* wq    = (const float*)d_in[3];
  const float* bq    = (const float*)d_in[4];
  const float* wkv   = (const float*)d_in[5];
  const float* bkv   = (const float*)d_in[6];
  const float* relb  = (const float*)d_in[7];
  const float* wproj = (const float*)d_in[8];
  const float* bproj = (const float*)d_in[9];
  const float* n2g   = (const float*)d_in[10];
  const float* n2b   = (const float*)d_in[11];
  const float* w1    = (const float*)d_in[12];
  const float* b1    = (const float*)d_in[13];
  const float* dwk   = (const float*)d_in[14];
  const float* dwb   = (const float*)d_in[15];
  const float* w2    = (const float*)d_in[16];
  const float* b2    = (const float*)d_in[17];

  char* ws = (char*)d_ws;
  u16*    wqkvT = (u16*)ws;                    //  24576 B
  u16*    wpT   = (u16*)(ws + 24576);          //   8192 B
  u16*    w1T   = (u16*)(ws + 32768);          //  32768 B
  u16*    w2T   = (u16*)(ws + 65536);          //  32768 B
  float*  biasx = (float*)(ws + 98304);        //  32768 B
  float2* mrs   = (float2*)(ws + 131072);      // 2359296 B
  float*  x1    = (float*)(ws + 2490368);      // 75497472 B (total ~78 MB)
  float*  outp  = (float*)d_out;

  k_prep<<<64, 256, 0, stream>>>(wq, wkv, wproj, w1, w2, relb, wqkvT, wpT, w1T, w2T, biasx);
  k_attn<<<2304, 512, 0, stream>>>(x, n1g, n1b, wqkvT, bq, bkv, biasx, wpT, bproj, mrs, x1);
  k_mlp<<<4608, 512, 0, stream>>>(x1, mrs, n2g, n2b, w1T, b1, dwk, dwb, w2T, b2, outp);
}

// Round 7
// 296.456 us; speedup vs baseline: 5.3413x; 1.1193x over previous
//
#include <hip/hip_runtime.h>
#include <hip/hip_bf16.h>
#include <math.h>

typedef unsigned short u16;
typedef unsigned int u32;
typedef __attribute__((ext_vector_type(8))) unsigned short us8;
typedef __attribute__((ext_vector_type(8))) __bf16 bf16x8;
typedef __attribute__((ext_vector_type(4))) float f32x4;

#define MFMA16(a, b, c) __builtin_amdgcn_mfma_f32_16x16x32_bf16((a), (b), (c), 0, 0, 0)

static __device__ __forceinline__ float bf2f(u16 u) {
  union { u32 i; float f; } v; v.i = ((u32)u) << 16; return v.f;
}
static __device__ __forceinline__ u16 f2bf(float f) {
  __hip_bfloat16 h = __float2bfloat16(f);
  return *reinterpret_cast<u16*>(&h);
}
static __device__ __forceinline__ u32 pk2bf(float lo, float hi) {
  return ((u32)f2bf(hi) << 16) | (u32)f2bf(lo);
}
static __device__ __forceinline__ float lo16(u32 v) {
  union { u32 i; float f; } u; u.i = v << 16; return u.f;
}
static __device__ __forceinline__ float hi16(u32 v) {
  union { u32 i; float f; } u; u.i = v & 0xFFFF0000u; return u.f;
}
static __device__ __forceinline__ bf16x8 ldfrag(const u16* p) {
  us8 v = *reinterpret_cast<const us8*>(p);
  return __builtin_bit_cast(bf16x8, v);
}
// sigmoid-gelu: x * sigmoid(1.702x)
static __device__ __forceinline__ float gelu_s(float x) {
  return x * __builtin_amdgcn_rcpf(1.0f + __expf(-1.702f * x));
}

#define NTOK 147456  // 384*384
#define NWX 48

// ---------------------------------------------------------------------------
// Prep: transpose weights to bf16 [o][c], expand rel bias table
// ---------------------------------------------------------------------------
__global__ __launch_bounds__(256) void k_prep(
    const float* __restrict__ wq, const float* __restrict__ wkv,
    const float* __restrict__ wproj, const float* __restrict__ w1,
    const float* __restrict__ w2, const float* __restrict__ relb,
    u16* __restrict__ wqkvT, u16* __restrict__ wpT,
    u16* __restrict__ w1T, u16* __restrict__ w2T, float* __restrict__ biasx)
{
  const int idx = blockIdx.x * 256 + threadIdx.x;
  const int NT = 64 * 256;
  for (int i = idx; i < 12288; i += NT) {
    int o = i >> 6, c = i & 63;
    wqkvT[i] = f2bf(o < 64 ? wq[c * 64 + o] : wkv[c * 128 + (o - 64)]);
  }
  for (int i = idx; i < 4096; i += NT) {
    int o = i >> 6, c = i & 63;
    wpT[i] = f2bf(wproj[c * 64 + o]);
  }
  for (int i = idx; i < 16384; i += NT) {
    int o = i >> 6, c = i & 63;
    w1T[i] = f2bf(w1[c * 256 + o]);
  }
  for (int i = idx; i < 16384; i += NT) {
    int o = i >> 8, c2 = i & 255;
    w2T[i] = f2bf(w2[c2 * 64 + o]);
  }
  for (int i = idx; i < 8192; i += NT) {
    int h = i >> 12, r = i & 4095, ii = r >> 6, j = r & 63;
    int dy = (ii >> 3) - (j >> 3) + 7, dx = (ii & 7) - (j & 7) + 7;
    biasx[i] = relb[(dy * 15 + dx) * 2 + h];
  }
}

// softmax of 4 tile-scores for one quarter of rows; writes P (bf16) to Pd
static __device__ __forceinline__ void softmax_rows(
    const f32x4* sc, const float* biasrow_base, int i0, int lg, int lr,
    u16* Pd)
{
#pragma unroll
  for (int r = 0; r < 4; ++r) {
    const int i = i0 + lg * 4 + r;
    const float* brow = biasrow_base + i * 64;
    float pv[4];
    float mx = -1e30f;
#pragma unroll
    for (int jt = 0; jt < 4; ++jt) {
      pv[jt] = fmaf(sc[jt][r], 0.17677669529663687f, brow[jt * 16 + lr]);
      mx = fmaxf(mx, pv[jt]);
    }
#pragma unroll
    for (int off = 1; off < 16; off <<= 1) mx = fmaxf(mx, __shfl_xor(mx, off));
    float sum = 0.f;
#pragma unroll
    for (int jt = 0; jt < 4; ++jt) { pv[jt] = __expf(pv[jt] - mx); sum += pv[jt]; }
#pragma unroll
    for (int off = 1; off < 16; off <<= 1) sum += __shfl_xor(sum, off);
    const float inv = __builtin_amdgcn_rcpf(sum);
#pragma unroll
    for (int jt = 0; jt < 4; ++jt)
      Pd[i * 72 + jt * 16 + lr] = f2bf(pv[jt] * inv);
  }
}

// ---------------------------------------------------------------------------
// Kernel 1: LN1 + windowed MHSA + proj + residual -> x1, plus LN2 stats -> mrs
// one block = 1 window, 256 thr, LDS 36864 B -> 4 blocks/CU, 3 barriers
// ---------------------------------------------------------------------------
__global__ __launch_bounds__(256, 4) void k_attn(
    const float* __restrict__ x,
    const float* __restrict__ n1g, const float* __restrict__ n1b,
    const u16* __restrict__ wqkvT, const float* __restrict__ bq,
    const float* __restrict__ bkv, const float* __restrict__ biasx,
    const u16* __restrict__ wpT, const float* __restrict__ bproj,
    float2* __restrict__ mrs, float* __restrict__ x1)
{
  __shared__ u16 xs[64 * 72];    // LN1 out, later P (head 0)
  __shared__ u16 qsm[64 * 72];   // Q, later P (head 1)
  __shared__ u16 ksm[64 * 72];   // K, later O
  __shared__ u16 vT[64 * 72];    // V transposed [ch][token]

  const int tid = threadIdx.x;
  const int wv = tid >> 6;
  const int ln = tid & 63;
  const int lg = ln >> 4, lr = ln & 15;

  const int blk = blockIdx.x;          // 4608 blocks, 1 window each
  const int b = blk / 2304;
  const int rem = blk - b * 2304;
  const int wy = rem / NWX, wx = rem - wy * NWX;

  // ---- load window + LN1 -> xs (4 adjacent lanes own one token) ----
  {
    const int t = tid >> 2, g = tid & 3;
    const int gy = wy * 8 + (t >> 3), gx = wx * 8 + (t & 7);
    const long rowbase = ((long)b * NTOK + gy * 384 + gx) * 64;
    float loc[16];
    float s0 = 0.f, s1 = 0.f;
#pragma unroll
    for (int k = 0; k < 16; k += 4) {
      float4 v4 = *reinterpret_cast<const float4*>(x + rowbase + g * 16 + k);
      loc[k] = v4.x; loc[k + 1] = v4.y; loc[k + 2] = v4.z; loc[k + 3] = v4.w;
    }
#pragma unroll
    for (int k = 0; k < 16; ++k) { s0 += loc[k]; s1 += loc[k] * loc[k]; }
    s0 += __shfl_xor(s0, 1); s0 += __shfl_xor(s0, 2);
    s1 += __shfl_xor(s1, 1); s1 += __shfl_xor(s1, 2);
    const float m = s0 * 0.015625f;
    const float var = s1 * 0.015625f - m * m;
    const float rs = rsqrtf(var + 1e-5f);
#pragma unroll
    for (int k = 0; k < 16; ++k) {
      int c = g * 16 + k;
      xs[t * 72 + c] = f2bf((loc[k] - m) * rs * n1g[c] + n1b[c]);
    }
  }
  __syncthreads();   // barrier 1

  // ---- QKV: [64x64] @ [64x192], bias preloaded into accumulator ----
  for (int q = 0; q < 12; ++q) {
    const int t = wv * 12 + q;
    const int i0 = (t & 3) * 16, n0 = (t >> 2) * 16;
    const int oc = n0 + lr;
    const float bias = (oc < 64) ? bq[oc] : bkv[oc - 64];
    f32x4 acc = { bias, bias, bias, bias };
    bf16x8 a0 = ldfrag(&xs[(i0 + lr) * 72 + lg * 8]);
    bf16x8 a1 = ldfrag(&xs[(i0 + lr) * 72 + 32 + lg * 8]);
    bf16x8 b0 = ldfrag(&wqkvT[(n0 + lr) * 64 + lg * 8]);
    bf16x8 b1 = ldfrag(&wqkvT[(n0 + lr) * 64 + 32 + lg * 8]);
    acc = MFMA16(a0, b0, acc);
    acc = MFMA16(a1, b1, acc);
#pragma unroll
    for (int r = 0; r < 4; ++r) {
      const int tok = i0 + lg * 4 + r;
      const float val = acc[r];
      if (oc < 64)       qsm[tok * 72 + oc] = f2bf(val);
      else if (oc < 128) ksm[tok * 72 + (oc - 64)] = f2bf(val);
      else               vT[(oc - 128) * 72 + tok] = f2bf(val);
    }
  }
  __syncthreads();   // barrier 2

  // ---- S (both heads) + softmax + P + PV -- no barriers (wave-private rows) ----
  const int i0 = wv * 16;
  f32x4 oacc[2][2];
  {
    bf16x8 aq0 = ldfrag(&qsm[(i0 + lr) * 72 + lg * 8]);
    bf16x8 aq1 = ldfrag(&qsm[(i0 + lr) * 72 + 32 + lg * 8]);
    f32x4 sc0[4], sc1[4];
#pragma unroll
    for (int jt = 0; jt < 4; ++jt) {
      f32x4 z = {};
      bf16x8 bk0 = ldfrag(&ksm[(jt * 16 + lr) * 72 + lg * 8]);
      bf16x8 bk1 = ldfrag(&ksm[(jt * 16 + lr) * 72 + 32 + lg * 8]);
      sc0[jt] = MFMA16(aq0, bk0, z);
      sc1[jt] = MFMA16(aq1, bk1, z);
    }
    softmax_rows(sc0, biasx, i0, lg, lr, xs);           // P head0 -> xs
    softmax_rows(sc1, biasx + 4096, i0, lg, lr, qsm);   // P head1 -> qsm

    // PV (reads own P rows; vT from barrier-2)
#pragma unroll
    for (int q = 0; q < 2; ++q) {
      f32x4 a0 = {}, a1 = {};
#pragma unroll
      for (int ks = 0; ks < 64; ks += 32) {
        a0 = MFMA16(ldfrag(&xs[(i0 + lr) * 72 + ks + lg * 8]),
                    ldfrag(&vT[(q * 16 + lr) * 72 + ks + lg * 8]), a0);
        a1 = MFMA16(ldfrag(&qsm[(i0 + lr) * 72 + ks + lg * 8]),
                    ldfrag(&vT[(32 + q * 16 + lr) * 72 + ks + lg * 8]), a1);
      }
      oacc[0][q] = a0;
      oacc[1][q] = a1;
    }
  }
  __syncthreads();   // barrier 3: all waves done reading ksm (S phase)

  // ---- O -> ksm (own rows) ----
#pragma unroll
  for (int h = 0; h < 2; ++h)
#pragma unroll
    for (int q = 0; q < 2; ++q) {
      const int ch = h * 32 + q * 16 + lr;
#pragma unroll
      for (int r = 0; r < 4; ++r)
        ksm[(i0 + lg * 4 + r) * 72 + ch] = f2bf(oacc[h][q][r]);
    }
  // no barrier: proj reads only this wave's own O rows

  // ---- proj + residual -> x1, plus LN2 stats -> mrs ----
  {
    float s[4] = {}, sq[4] = {};
#pragma unroll
    for (int q = 0; q < 4; ++q) {
      const int o0 = q * 16;
      const int oc = o0 + lr;
      const float bp = bproj[oc];
      f32x4 acc = { bp, bp, bp, bp };
#pragma unroll
      for (int ks = 0; ks < 64; ks += 32) {
        bf16x8 ao = ldfrag(&ksm[(i0 + lr) * 72 + ks + lg * 8]);
        bf16x8 bw = ldfrag(&wpT[(o0 + lr) * 64 + ks + lg * 8]);
        acc = MFMA16(ao, bw, acc);
      }
#pragma unroll
      for (int r = 0; r < 4; ++r) {
        const int tok = i0 + lg * 4 + r;
        const int gy = wy * 8 + (tok >> 3), gx = wx * 8 + (tok & 7);
        const long idx = ((long)b * NTOK + gy * 384 + gx) * 64 + oc;
        const float v = x[idx] + acc[r];
        x1[idx] = v;
        s[r] += v; sq[r] += v * v;
      }
    }
#pragma unroll
    for (int r = 0; r < 4; ++r) {
      float ss = s[r], qq = sq[r];
#pragma unroll
      for (int off = 1; off < 16; off <<= 1) {
        ss += __shfl_xor(ss, off);
        qq += __shfl_xor(qq, off);
      }
      if (lr == 0) {
        const float m = ss * 0.015625f;
        const float var = qq * 0.015625f - m * m;
        const int tok = i0 + lg * 4 + r;
        const int gy = wy * 8 + (tok >> 3), gx = wx * 8 + (tok & 7);
        mrs[(long)b * NTOK + gy * 384 + gx] = make_float2(m, rsqrtf(var + 1e-5f));
      }
    }
  }
}

// ---------------------------------------------------------------------------
// Kernel 2: LN2-apply + fc1 + gelu + dwconv3x3 + gelu + fc2 + residual
// HID chunked by 64; htbT transposed+packed; 38.8KB LDS -> 4 blocks/CU
// ---------------------------------------------------------------------------
__global__ __launch_bounds__(512, 8) void k_mlp(
    const float* __restrict__ x1, const float2* __restrict__ mrs,
    const float* __restrict__ n2g, const float* __restrict__ n2b,
    const u16* __restrict__ w1T, const float* __restrict__ pb1,
    const float* __restrict__ dwk, const float* __restrict__ dwb,
    const u16* __restrict__ w2T, const float* __restrict__ pb2,
    float* __restrict__ out)
{
  __shared__ u16 xln[112 * 72];    // LN2'd halo tile (bf16), rows 100..111 zero
  __shared__ u16 htbT[64 * 102];   // gelu(fc1) chunk, TRANSPOSED [ch][pos]
  __shared__ u16 g2[64 * 72];      // gelu(dwconv) chunk (bf16) [token][ch]
  __shared__ float flag[112];      // 1.0 if halo pos in-image else 0.0

  const int tid = threadIdx.x;
  const int wave = tid >> 6, ln = tid & 63;
  const int lg = ln >> 4, lr = ln & 15;
  const int blk = blockIdx.x;
  const int b = blk / 2304;
  const int rem = blk - b * 2304;
  const int ty0 = (rem / NWX) * 8, tx0 = (rem - (rem / NWX) * NWX) * 8;

  if (tid < 112) {
    float f = 0.f;
    if (tid < 100) {
      const int py = ty0 + tid / 10 - 1, px = tx0 + tid % 10 - 1;
      if (py >= 0 && py < 384 && px >= 0 && px < 384) f = 1.f;
    }
    flag[tid] = f;
  }

  // ---- LN2 apply over halo (one wave per row) ----
  {
    const float gg = n2g[ln], bb = n2b[ln];
    for (int p = wave; p < 112; p += 8) {
      u16 o = 0;
      if (p < 100) {
        const int py = ty0 + p / 10 - 1, px = tx0 + p % 10 - 1;
        if (py >= 0 && py < 384 && px >= 0 && px < 384) {
          const long tok = (long)b * NTOK + py * 384 + px;
          const float2 mr = mrs[tok];
          const float v = x1[tok * 64 + ln];
          o = f2bf((v - mr.x) * mr.y * gg + bb);
        }
      }
      xln[p * 72 + ln] = o;
    }
  }
  __syncthreads();   // xln + flag ready

  // fc2 accumulators, bias preloaded
  const int fc2_oc = ((wave * 2) >> 2) * 16 + lr;
  const float fc2_b = pb2[fc2_oc];
  f32x4 facc[2] = { { fc2_b, fc2_b, fc2_b, fc2_b }, { fc2_b, fc2_b, fc2_b, fc2_b } };

#pragma unroll 1
  for (int ch = 0; ch < 4; ++ch) {
    // ---- fc1 chunk + gelu -> htbT (packed pairs, 2x ds_write_b32) ----
    for (int t = wave; t < 28; t += 8) {
      const int i0 = (t >> 2) * 16, n0 = (t & 3) * 16;
      const int oc = n0 + lr;
      const float bias = pb1[ch * 64 + oc];
      f32x4 acc = { bias, bias, bias, bias };
      bf16x8 a0 = ldfrag(&xln[(i0 + lr) * 72 + lg * 8]);
      bf16x8 a1 = ldfrag(&xln[(i0 + lr) * 72 + 32 + lg * 8]);
      bf16x8 b0 = ldfrag(&w1T[(ch * 64 + n0 + lr) * 64 + lg * 8]);
      bf16x8 b1 = ldfrag(&w1T[(ch * 64 + n0 + lr) * 64 + 32 + lg * 8]);
      acc = MFMA16(a0, b0, acc);
      acc = MFMA16(a1, b1, acc);
      const int p0 = i0 + lg * 4;
      if (p0 < 100) {
        float g0 = gelu_s(acc[0]) * flag[p0 + 0];
        float g1 = gelu_s(acc[1]) * flag[p0 + 1];
        float g2v = gelu_s(acc[2]) * flag[p0 + 2];
        float g3 = gelu_s(acc[3]) * flag[p0 + 3];
        u32* dst = reinterpret_cast<u32*>(&htbT[oc * 102 + p0]);
        dst[0] = pk2bf(g0, g1);
        dst[1] = pk2bf(g2v, g3);
      }
    }
    __syncthreads();

    // ---- dwconv 3x3 + gelu -> g2 (wave = token row, lane = channel) ----
    {
      const int gch = ch * 64 + ln;
      float wk[9];
      const float db = dwb[gch];
#pragma unroll
      for (int q = 0; q < 9; ++q) wk[q] = dwk[gch * 9 + q];
      const u16* rowbase = &htbT[ln * 102];
      const u32* r0 = reinterpret_cast<const u32*>(rowbase + (wave + 0) * 10);
      const u32* r1 = reinterpret_cast<const u32*>(rowbase + (wave + 1) * 10);
      const u32* r2 = reinterpret_cast<const u32*>(rowbase + (wave + 2) * 10);
      u32 v;
      float a0,b0,c0,d0, a1,b1,c1,d1, a2,b2,c2,d2;
      v = r0[0]; a0 = lo16(v); b0 = hi16(v);
      v = r0[1]; c0 = lo16(v); d0 = hi16(v);
      v = r1[0]; a1 = lo16(v); b1 = hi16(v);
      v = r1[1]; c1 = lo16(v); d1 = hi16(v);
      v = r2[0]; a2 = lo16(v); b2 = hi16(v);
      v = r2[1]; c2 = lo16(v); d2 = hi16(v);
#pragma unroll
      for (int s = 0; s < 4; ++s) {
        float e0 = db + a0 * wk[0] + b0 * wk[1] + c0 * wk[2]
                      + a1 * wk[3] + b1 * wk[4] + c1 * wk[5]
                      + a2 * wk[6] + b2 * wk[7] + c2 * wk[8];
        float e1 = db + b0 * wk[0] + c0 * wk[1] + d0 * wk[2]
                      + b1 * wk[3] + c1 * wk[4] + d1 * wk[5]
                      + b2 * wk[6] + c2 * wk[7] + d2 * wk[8];
        g2[(wave * 8 + 2 * s) * 72 + ln]     = f2bf(gelu_s(e0));
        g2[(wave * 8 + 2 * s + 1) * 72 + ln] = f2bf(gelu_s(e1));
        if (s < 3) {
          v = r0[s + 2]; a0 = c0; b0 = d0; c0 = lo16(v); d0 = hi16(v);
          v = r1[s + 2]; a1 = c1; b1 = d1; c1 = lo16(v); d1 = hi16(v);
          v = r2[s + 2]; a2 = c2; b2 = d2; c2 = lo16(v); d2 = hi16(v);
        }
      }
    }
    __syncthreads();

    // ---- fc2 partial accumulate ----
#pragma unroll
    for (int q = 0; q < 2; ++q) {
      const int t = wave * 2 + q;
      const int i0 = (t & 3) * 16, o0 = (t >> 2) * 16;
      bf16x8 ag0 = ldfrag(&g2[(i0 + lr) * 72 + lg * 8]);
      bf16x8 ag1 = ldfrag(&g2[(i0 + lr) * 72 + 32 + lg * 8]);
      bf16x8 bw0 = ldfrag(&w2T[(o0 + lr) * 256 + ch * 64 + lg * 8]);
      bf16x8 bw1 = ldfrag(&w2T[(o0 + lr) * 256 + ch * 64 + 32 + lg * 8]);
      facc[q] = MFMA16(ag0, bw0, facc[q]);
      facc[q] = MFMA16(ag1, bw1, facc[q]);
    }
  }

  // ---- epilogue: + residual -> out (bias already in facc) ----
#pragma unroll
  for (int q = 0; q < 2; ++q) {
    const int t = wave * 2 + q;
    const int i0 = (t & 3) * 16, o0 = (t >> 2) * 16;
    const int oc = o0 + lr;
#pragma unroll
    for (int r = 0; r < 4; ++r) {
      const int token = i0 + lg * 4 + r;
      const int gy = ty0 + (token >> 3), gx = tx0 + (token & 7);
      const long idx = ((long)b * NTOK + gy * 384 + gx) * 64 + oc;
      out[idx] = x1[idx] + facc[q][r];
    }
  }
}

extern "C" void kernel_launch(void* const* d_in, const int* in_sizes, int n_in,
                              void* d_out, int out_size, void* d_ws, size_t ws_size,
                              hipStream_t stream) {
  const float* x     = (const float*)d_in[0];
  const float* n1g   = (const float*)d_in[1];
  const float* n1b   = (const float*)d_in[2];
  const float* wq    = (const float*)d_in[3];
  const float* bq    = (const float*)d_in[4];
  const float* wkv   = (const float*)d_in[5];
  const float* bkv   = (const float*)d_in[6];
  const float* relb  = (const float*)d_in[7];
  const float* wproj = (const float*)d_in[8];
  const float* bproj = (const float*)d_in[9];
  const float* n2g   = (const float*)d_in[10];
  const float* n2b   = (const float*)d_in[11];
  const float* w1    = (const float*)d_in[12];
  const float* b1    = (const float*)d_in[13];
  const float* dwk   = (const float*)d_in[14];
  const float* dwb   = (const float*)d_in[15];
  const float* w2    = (const float*)d_in[16];
  const float* b2    = (const float*)d_in[17];

  char* ws = (char*)d_ws;
  u16*    wqkvT = (u16*)ws;                    //  24576 B
  u16*    wpT   = (u16*)(ws + 24576);          //   8192 B
  u16*    w1T   = (u16*)(ws + 32768);          //  32768 B
  u16*    w2T   = (u16*)(ws + 65536);          //  32768 B
  float*  biasx = (float*)(ws + 98304);        //  32768 B
  float2* mrs   = (float2*)(ws + 131072);      // 2359296 B
  float*  x1    = (float*)(ws + 2490368);      // 75497472 B (total ~78 MB)
  float*  outp  = (float*)d_out;

  k_prep<<<64, 256, 0, stream>>>(wq, wkv, wproj, w1, w2, relb, wqkvT, wpT, w1T, w2T, biasx);
  k_attn<<<4608, 256, 0, stream>>>(x, n1g, n1b, wqkvT, bq, bkv, biasx, wpT, bproj, mrs, x1);
  k_mlp<<<4608, 512, 0, stream>>>(x1, mrs, n2g, n2b, w1T, b1, dwk, dwb, w2T, b2, outp);
}

// Round 8
// 214.209 us; speedup vs baseline: 7.3921x; 1.3840x over previous
//
#include <hip/hip_runtime.h>
#include <hip/hip_bf16.h>
#include <math.h>

typedef unsigned short u16;
typedef unsigned int u32;
typedef __attribute__((ext_vector_type(8))) unsigned short us8;
typedef __attribute__((ext_vector_type(8))) __bf16 bf16x8;
typedef __attribute__((ext_vector_type(4))) float f32x4;

#define MFMA16(a, b, c) __builtin_amdgcn_mfma_f32_16x16x32_bf16((a), (b), (c), 0, 0, 0)

static __device__ __forceinline__ float bf2f(u16 u) {
  union { u32 i; float f; } v; v.i = ((u32)u) << 16; return v.f;
}
static __device__ __forceinline__ u16 f2bf(float f) {
  __hip_bfloat16 h = __float2bfloat16(f);
  return *reinterpret_cast<u16*>(&h);
}
static __device__ __forceinline__ u32 pk2bf(float lo, float hi) {
  return ((u32)f2bf(hi) << 16) | (u32)f2bf(lo);
}
static __device__ __forceinline__ float lo16(u32 v) {
  union { u32 i; float f; } u; u.i = v << 16; return u.f;
}
static __device__ __forceinline__ float hi16(u32 v) {
  union { u32 i; float f; } u; u.i = v & 0xFFFF0000u; return u.f;
}
static __device__ __forceinline__ bf16x8 ldfrag(const u16* p) {
  us8 v = *reinterpret_cast<const us8*>(p);
  return __builtin_bit_cast(bf16x8, v);
}
// sigmoid-gelu: x * sigmoid(1.702x)
static __device__ __forceinline__ float gelu_s(float x) {
  return x * __builtin_amdgcn_rcpf(1.0f + __expf(-1.702f * x));
}

#define NTOK 147456  // 384*384
#define NWX 48

// ---------------------------------------------------------------------------
// Prep: transpose weights to bf16 [o][c], expand rel bias table
// ---------------------------------------------------------------------------
__global__ __launch_bounds__(256) void k_prep(
    const float* __restrict__ wq, const float* __restrict__ wkv,
    const float* __restrict__ wproj, const float* __restrict__ w1,
    const float* __restrict__ w2, const float* __restrict__ relb,
    u16* __restrict__ wqkvT, u16* __restrict__ wpT,
    u16* __restrict__ w1T, u16* __restrict__ w2T, float* __restrict__ biasx)
{
  const int idx = blockIdx.x * 256 + threadIdx.x;
  const int NT = 64 * 256;
  for (int i = idx; i < 12288; i += NT) {
    int o = i >> 6, c = i & 63;
    wqkvT[i] = f2bf(o < 64 ? wq[c * 64 + o] : wkv[c * 128 + (o - 64)]);
  }
  for (int i = idx; i < 4096; i += NT) {
    int o = i >> 6, c = i & 63;
    wpT[i] = f2bf(wproj[c * 64 + o]);
  }
  for (int i = idx; i < 16384; i += NT) {
    int o = i >> 6, c = i & 63;
    w1T[i] = f2bf(w1[c * 256 + o]);
  }
  for (int i = idx; i < 16384; i += NT) {
    int o = i >> 8, c2 = i & 255;
    w2T[i] = f2bf(w2[c2 * 64 + o]);
  }
  for (int i = idx; i < 8192; i += NT) {
    int h = i >> 12, r = i & 4095, ii = r >> 6, j = r & 63;
    int dy = (ii >> 3) - (j >> 3) + 7, dx = (ii & 7) - (j & 7) + 7;
    biasx[i] = relb[(dy * 15 + dx) * 2 + h];
  }
}

// softmax of 4 tile-scores for one quarter of rows; writes P (bf16) to Pd
static __device__ __forceinline__ void softmax_rows(
    const f32x4* sc, const float* biasrow_base, int i0, int lg, int lr,
    u16* Pd)
{
#pragma unroll
  for (int r = 0; r < 4; ++r) {
    const int i = i0 + lg * 4 + r;
    const float* brow = biasrow_base + i * 64;
    float pv[4];
    float mx = -1e30f;
#pragma unroll
    for (int jt = 0; jt < 4; ++jt) {
      pv[jt] = fmaf(sc[jt][r], 0.17677669529663687f, brow[jt * 16 + lr]);
      mx = fmaxf(mx, pv[jt]);
    }
#pragma unroll
    for (int off = 1; off < 16; off <<= 1) mx = fmaxf(mx, __shfl_xor(mx, off));
    float sum = 0.f;
#pragma unroll
    for (int jt = 0; jt < 4; ++jt) { pv[jt] = __expf(pv[jt] - mx); sum += pv[jt]; }
#pragma unroll
    for (int off = 1; off < 16; off <<= 1) sum += __shfl_xor(sum, off);
    const float inv = __builtin_amdgcn_rcpf(sum);
#pragma unroll
    for (int jt = 0; jt < 4; ++jt)
      Pd[i * 72 + jt * 16 + lr] = f2bf(pv[jt] * inv);
  }
}

// ---------------------------------------------------------------------------
// Kernel 1: LN1 + windowed MHSA + proj + residual -> x1, plus LN2 stats -> mrs
// one block = 1 window, 256 thr, LDS 36864 B -> 4 blocks/CU, 3 barriers
// ---------------------------------------------------------------------------
__global__ __launch_bounds__(256, 4) void k_attn(
    const float* __restrict__ x,
    const float* __restrict__ n1g, const float* __restrict__ n1b,
    const u16* __restrict__ wqkvT, const float* __restrict__ bq,
    const float* __restrict__ bkv, const float* __restrict__ biasx,
    const u16* __restrict__ wpT, const float* __restrict__ bproj,
    float2* __restrict__ mrs, float* __restrict__ x1)
{
  __shared__ u16 xs[64 * 72];    // LN1 out, later P (head 0)
  __shared__ u16 qsm[64 * 72];   // Q, later P (head 1)
  __shared__ u16 ksm[64 * 72];   // K, later O
  __shared__ u16 vT[64 * 72];    // V transposed [ch][token]

  const int tid = threadIdx.x;
  const int wv = tid >> 6;
  const int ln = tid & 63;
  const int lg = ln >> 4, lr = ln & 15;

  const int blk = blockIdx.x;          // 4608 blocks, 1 window each
  const int b = blk / 2304;
  const int rem = blk - b * 2304;
  const int wy = rem / NWX, wx = rem - wy * NWX;

  // ---- load window + LN1 -> xs (4 adjacent lanes own one token) ----
  {
    const int t = tid >> 2, g = tid & 3;
    const int gy = wy * 8 + (t >> 3), gx = wx * 8 + (t & 7);
    const long rowbase = ((long)b * NTOK + gy * 384 + gx) * 64;
    float loc[16];
    float s0 = 0.f, s1 = 0.f;
#pragma unroll
    for (int k = 0; k < 16; k += 4) {
      float4 v4 = *reinterpret_cast<const float4*>(x + rowbase + g * 16 + k);
      loc[k] = v4.x; loc[k + 1] = v4.y; loc[k + 2] = v4.z; loc[k + 3] = v4.w;
    }
#pragma unroll
    for (int k = 0; k < 16; ++k) { s0 += loc[k]; s1 += loc[k] * loc[k]; }
    s0 += __shfl_xor(s0, 1); s0 += __shfl_xor(s0, 2);
    s1 += __shfl_xor(s1, 1); s1 += __shfl_xor(s1, 2);
    const float m = s0 * 0.015625f;
    const float var = s1 * 0.015625f - m * m;
    const float rs = rsqrtf(var + 1e-5f);
#pragma unroll
    for (int k = 0; k < 16; ++k) {
      int c = g * 16 + k;
      xs[t * 72 + c] = f2bf((loc[k] - m) * rs * n1g[c] + n1b[c]);
    }
  }
  __syncthreads();   // barrier 1

  // ---- QKV: 3 n-groups per wave (hoisted B-frags), 4 i-tiles each ----
#pragma unroll
  for (int qq = 0; qq < 3; ++qq) {
    const int grp = 3 * wv + qq;           // 0..11 (wave-uniform)
    const int n0 = grp * 16;
    const int oc = n0 + lr;
    const float bias = (grp < 4) ? bq[oc] : bkv[oc - 64];
    bf16x8 b0 = ldfrag(&wqkvT[oc * 64 + lg * 8]);
    bf16x8 b1 = ldfrag(&wqkvT[oc * 64 + 32 + lg * 8]);
#pragma unroll
    for (int ii = 0; ii < 4; ++ii) {
      const int i0 = ii * 16;
      f32x4 acc = { bias, bias, bias, bias };
      acc = MFMA16(ldfrag(&xs[(i0 + lr) * 72 + lg * 8]), b0, acc);
      acc = MFMA16(ldfrag(&xs[(i0 + lr) * 72 + 32 + lg * 8]), b1, acc);
      const int tok0 = i0 + lg * 4;
      if (grp < 4) {
#pragma unroll
        for (int r = 0; r < 4; ++r) qsm[(tok0 + r) * 72 + oc] = f2bf(acc[r]);
      } else if (grp < 8) {
#pragma unroll
        for (int r = 0; r < 4; ++r) ksm[(tok0 + r) * 72 + (oc - 64)] = f2bf(acc[r]);
      } else {
        u32* dst = reinterpret_cast<u32*>(&vT[(oc - 128) * 72 + tok0]);
        dst[0] = pk2bf(acc[0], acc[1]);
        dst[1] = pk2bf(acc[2], acc[3]);
      }
    }
  }
  __syncthreads();   // barrier 2

  // ---- S (both heads) + softmax + P + PV -- no barriers (wave-private rows) ----
  const int i0 = wv * 16;
  f32x4 oacc[2][2];
  {
    bf16x8 aq0 = ldfrag(&qsm[(i0 + lr) * 72 + lg * 8]);
    bf16x8 aq1 = ldfrag(&qsm[(i0 + lr) * 72 + 32 + lg * 8]);
    f32x4 sc0[4], sc1[4];
#pragma unroll
    for (int jt = 0; jt < 4; ++jt) {
      f32x4 z = {};
      bf16x8 bk0 = ldfrag(&ksm[(jt * 16 + lr) * 72 + lg * 8]);
      bf16x8 bk1 = ldfrag(&ksm[(jt * 16 + lr) * 72 + 32 + lg * 8]);
      sc0[jt] = MFMA16(aq0, bk0, z);
      sc1[jt] = MFMA16(aq1, bk1, z);
    }
    softmax_rows(sc0, biasx, i0, lg, lr, xs);           // P head0 -> xs
    softmax_rows(sc1, biasx + 4096, i0, lg, lr, qsm);   // P head1 -> qsm

    // PV (reads own P rows; vT from barrier-2)
#pragma unroll
    for (int q = 0; q < 2; ++q) {
      f32x4 a0 = {}, a1 = {};
#pragma unroll
      for (int ks = 0; ks < 64; ks += 32) {
        a0 = MFMA16(ldfrag(&xs[(i0 + lr) * 72 + ks + lg * 8]),
                    ldfrag(&vT[(q * 16 + lr) * 72 + ks + lg * 8]), a0);
        a1 = MFMA16(ldfrag(&qsm[(i0 + lr) * 72 + ks + lg * 8]),
                    ldfrag(&vT[(32 + q * 16 + lr) * 72 + ks + lg * 8]), a1);
      }
      oacc[0][q] = a0;
      oacc[1][q] = a1;
    }
  }
  __syncthreads();   // barrier 3: all waves done reading ksm (S phase)

  // ---- O -> ksm (own rows) ----
#pragma unroll
  for (int h = 0; h < 2; ++h)
#pragma unroll
    for (int q = 0; q < 2; ++q) {
      const int ch = h * 32 + q * 16 + lr;
#pragma unroll
      for (int r = 0; r < 4; ++r)
        ksm[(i0 + lg * 4 + r) * 72 + ch] = f2bf(oacc[h][q][r]);
    }
  // no barrier: proj reads only this wave's own O rows

  // ---- proj + residual -> x1, plus LN2 stats -> mrs ----
  {
    float s[4] = {}, sq[4] = {};
#pragma unroll
    for (int q = 0; q < 4; ++q) {
      const int o0 = q * 16;
      const int oc = o0 + lr;
      const float bp = bproj[oc];
      f32x4 acc = { bp, bp, bp, bp };
#pragma unroll
      for (int ks = 0; ks < 64; ks += 32) {
        bf16x8 ao = ldfrag(&ksm[(i0 + lr) * 72 + ks + lg * 8]);
        bf16x8 bw = ldfrag(&wpT[(o0 + lr) * 64 + ks + lg * 8]);
        acc = MFMA16(ao, bw, acc);
      }
#pragma unroll
      for (int r = 0; r < 4; ++r) {
        const int tok = i0 + lg * 4 + r;
        const int gy = wy * 8 + (tok >> 3), gx = wx * 8 + (tok & 7);
        const long idx = ((long)b * NTOK + gy * 384 + gx) * 64 + oc;
        const float v = x[idx] + acc[r];
        x1[idx] = v;
        s[r] += v; sq[r] += v * v;
      }
    }
#pragma unroll
    for (int r = 0; r < 4; ++r) {
      float ss = s[r], qq = sq[r];
#pragma unroll
      for (int off = 1; off < 16; off <<= 1) {
        ss += __shfl_xor(ss, off);
        qq += __shfl_xor(qq, off);
      }
      if (lr == 0) {
        const float m = ss * 0.015625f;
        const float var = qq * 0.015625f - m * m;
        const int tok = i0 + lg * 4 + r;
        const int gy = wy * 8 + (tok >> 3), gx = wx * 8 + (tok & 7);
        mrs[(long)b * NTOK + gy * 384 + gx] = make_float2(m, rsqrtf(var + 1e-5f));
      }
    }
  }
}

// ---------------------------------------------------------------------------
// Kernel 2: LN2-apply + fc1 + gelu + dwconv3x3 + gelu + fc2 + residual
// HID chunked by 64; unrolled/hoisted; 38.9KB LDS -> 4 blocks/CU
// ---------------------------------------------------------------------------
__global__ __launch_bounds__(512, 8) void k_mlp(
    const float* __restrict__ x1, const float2* __restrict__ mrs,
    const float* __restrict__ n2g, const float* __restrict__ n2b,
    const u16* __restrict__ w1T, const float* __restrict__ pb1,
    const float* __restrict__ dwk, const float* __restrict__ dwb,
    const u16* __restrict__ w2T, const float* __restrict__ pb2,
    float* __restrict__ out)
{
  __shared__ u16 xln[112 * 72];    // LN2'd halo tile (bf16), rows 100..111 zero
  __shared__ u16 htbT[64 * 102];   // gelu(fc1) chunk, TRANSPOSED [ch][pos]
  __shared__ u16 g2[64 * 72];      // gelu(dwconv) chunk (bf16) [token][ch]
  __shared__ float flag[112];      // 1.0 if halo pos in-image else 0.0

  const int tid = threadIdx.x;
  const int wave = tid >> 6, ln = tid & 63;
  const int lg = ln >> 4, lr = ln & 15;
  const int blk = blockIdx.x;
  const int b = blk / 2304;
  const int rem = blk - b * 2304;
  const int ty0 = (rem / NWX) * 8, tx0 = (rem - (rem / NWX) * NWX) * 8;

  if (tid < 112) {
    float f = 0.f;
    if (tid < 100) {
      const int py = ty0 + tid / 10 - 1, px = tx0 + tid % 10 - 1;
      if (py >= 0 && py < 384 && px >= 0 && px < 384) f = 1.f;
    }
    flag[tid] = f;
  }

  // ---- LN2 apply over halo (one wave per row, static unroll) ----
  {
    const float gg = n2g[ln], bb = n2b[ln];
#pragma unroll
    for (int j = 0; j < 14; ++j) {
      const int p = j * 8 + wave;
      u16 o = 0;
      if (p < 100) {
        const int py = ty0 + p / 10 - 1, px = tx0 + p % 10 - 1;
        if (py >= 0 && py < 384 && px >= 0 && px < 384) {
          const long tok = (long)b * NTOK + py * 384 + px;
          const float2 mr = mrs[tok];
          const float v = x1[tok * 64 + ln];
          o = f2bf((v - mr.x) * mr.y * gg + bb);
        }
      }
      xln[p * 72 + ln] = o;
    }
  }
  __syncthreads();   // xln + flag ready

  // wave-constant tile coordinates
  const int n0f = (wave & 3) * 16;       // fc1 col-tile base (const per wave)
  const int i0b = (wave >> 2) * 16;      // fc1 row-tile base: 0 or 16
  const int ocf = n0f + lr;
  const int o0  = (wave >> 1) * 16;      // fc2 out-col tile
  const int i0q = ((wave * 2) & 3) * 16; // fc2 row tile base (q=0)
  const int oc2 = o0 + lr;
  const float fc2_b = pb2[oc2];
  f32x4 facc[2] = { { fc2_b, fc2_b, fc2_b, fc2_b }, { fc2_b, fc2_b, fc2_b, fc2_b } };

#pragma unroll 1
  for (int ch = 0; ch < 4; ++ch) {
    // ---- fc1 chunk + gelu -> htbT (B-frags hoisted, k statically unrolled) ----
    {
      const u16* wbase = &w1T[(ch * 64 + ocf) * 64 + lg * 8];
      bf16x8 wb0 = ldfrag(wbase);
      bf16x8 wb1 = ldfrag(wbase + 32);
      const float bias1 = pb1[ch * 64 + ocf];
#pragma unroll
      for (int k = 0; k < 4; ++k) {
        const int i0 = i0b + k * 32;
        if (i0 < 112) {
          f32x4 acc = { bias1, bias1, bias1, bias1 };
          acc = MFMA16(ldfrag(&xln[(i0 + lr) * 72 + lg * 8]), wb0, acc);
          acc = MFMA16(ldfrag(&xln[(i0 + lr) * 72 + 32 + lg * 8]), wb1, acc);
          const int p0 = i0 + lg * 4;
          if (p0 < 100) {
            float g0 = gelu_s(acc[0]) * flag[p0 + 0];
            float g1 = gelu_s(acc[1]) * flag[p0 + 1];
            float g2v = gelu_s(acc[2]) * flag[p0 + 2];
            float g3 = gelu_s(acc[3]) * flag[p0 + 3];
            u32* dst = reinterpret_cast<u32*>(&htbT[ocf * 102 + p0]);
            dst[0] = pk2bf(g0, g1);
            dst[1] = pk2bf(g2v, g3);
          }
        }
      }
    }
    __syncthreads();

    // ---- dwconv 3x3 + gelu -> g2 (wave = token row, lane = channel) ----
    {
      const int gch = ch * 64 + ln;
      float wk[9];
      const float db = dwb[gch];
#pragma unroll
      for (int q = 0; q < 9; ++q) wk[q] = dwk[gch * 9 + q];
      const u16* rowbase = &htbT[ln * 102];
      const u32* r0 = reinterpret_cast<const u32*>(rowbase + (wave + 0) * 10);
      const u32* r1 = reinterpret_cast<const u32*>(rowbase + (wave + 1) * 10);
      const u32* r2 = reinterpret_cast<const u32*>(rowbase + (wave + 2) * 10);
      u32 v;
      float a0,b0,c0,d0, a1,b1,c1,d1, a2,b2,c2,d2;
      v = r0[0]; a0 = lo16(v); b0 = hi16(v);
      v = r0[1]; c0 = lo16(v); d0 = hi16(v);
      v = r1[0]; a1 = lo16(v); b1 = hi16(v);
      v = r1[1]; c1 = lo16(v); d1 = hi16(v);
      v = r2[0]; a2 = lo16(v); b2 = hi16(v);
      v = r2[1]; c2 = lo16(v); d2 = hi16(v);
#pragma unroll
      for (int s = 0; s < 4; ++s) {
        float e0 = db + a0 * wk[0] + b0 * wk[1] + c0 * wk[2]
                      + a1 * wk[3] + b1 * wk[4] + c1 * wk[5]
                      + a2 * wk[6] + b2 * wk[7] + c2 * wk[8];
        float e1 = db + b0 * wk[0] + c0 * wk[1] + d0 * wk[2]
                      + b1 * wk[3] + c1 * wk[4] + d1 * wk[5]
                      + b2 * wk[6] + c2 * wk[7] + d2 * wk[8];
        g2[(wave * 8 + 2 * s) * 72 + ln]     = f2bf(gelu_s(e0));
        g2[(wave * 8 + 2 * s + 1) * 72 + ln] = f2bf(gelu_s(e1));
        if (s < 3) {
          v = r0[s + 2]; a0 = c0; b0 = d0; c0 = lo16(v); d0 = hi16(v);
          v = r1[s + 2]; a1 = c1; b1 = d1; c1 = lo16(v); d1 = hi16(v);
          v = r2[s + 2]; a2 = c2; b2 = d2; c2 = lo16(v); d2 = hi16(v);
        }
      }
    }
    __syncthreads();

    // ---- fc2 partial accumulate (B-frags hoisted, shared by q=0,1) ----
    {
      const u16* wbase2 = &w2T[oc2 * 256 + ch * 64 + lg * 8];
      bf16x8 bw0 = ldfrag(wbase2);
      bf16x8 bw1 = ldfrag(wbase2 + 32);
#pragma unroll
      for (int q = 0; q < 2; ++q) {
        const int i0 = i0q + q * 16;
        bf16x8 ag0 = ldfrag(&g2[(i0 + lr) * 72 + lg * 8]);
        bf16x8 ag1 = ldfrag(&g2[(i0 + lr) * 72 + 32 + lg * 8]);
        facc[q] = MFMA16(ag0, bw0, facc[q]);
        facc[q] = MFMA16(ag1, bw1, facc[q]);
      }
    }
  }

  // ---- epilogue: + residual -> out (bias already in facc) ----
#pragma unroll
  for (int q = 0; q < 2; ++q) {
    const int i0 = i0q + q * 16;
#pragma unroll
    for (int r = 0; r < 4; ++r) {
      const int token = i0 + lg * 4 + r;
      const int gy = ty0 + (token >> 3), gx = tx0 + (token & 7);
      const long idx = ((long)b * NTOK + gy * 384 + gx) * 64 + oc2;
      out[idx] = x1[idx] + facc[q][r];
    }
  }
}

extern "C" void kernel_launch(void* const* d_in, const int* in_sizes, int n_in,
                              void* d_out, int out_size, void* d_ws, size_t ws_size,
                              hipStream_t stream) {
  const float* x     = (const float*)d_in[0];
  const float* n1g   = (const float*)d_in[1];
  const float* n1b   = (const float*)d_in[2];
  const float* wq    = (const float*)d_in[3];
  const float* bq    = (const float*)d_in[4];
  const float* wkv   = (const float*)d_in[5];
  const float* bkv   = (const float*)d_in[6];
  const float* relb  = (const float*)d_in[7];
  const float* wproj = (const float*)d_in[8];
  const float* bproj = (const float*)d_in[9];
  const float* n2g   = (const float*)d_in[10];
  const float* n2b   = (const float*)d_in[11];
  const float* w1    = (const float*)d_in[12];
  const float* b1    = (const float*)d_in[13];
  const float* dwk   = (const float*)d_in[14];
  const float* dwb   = (const float*)d_in[15];
  const float* w2    = (const float*)d_in[16];
  const float* b2    = (const float*)d_in[17];

  char* ws = (char*)d_ws;
  u16*    wqkvT = (u16*)ws;                    //  24576 B
  u16*    wpT   = (u16*)(ws + 24576);          //   8192 B
  u16*    w1T   = (u16*)(ws + 32768);          //  32768 B
  u16*    w2T   = (u16*)(ws + 65536);          //  32768 B
  float*  biasx = (float*)(ws + 98304);        //  32768 B
  float2* mrs   = (float2*)(ws + 131072);      // 2359296 B
  float*  x1    = (float*)(ws + 2490368);      // 75497472 B (total ~78 MB)
  float*  outp  = (float*)d_out;

  k_prep<<<64, 256, 0, stream>>>(wq, wkv, wproj, w1, w2, relb, wqkvT, wpT, w1T, w2T, biasx);
  k_attn<<<4608, 256, 0, stream>>>(x, n1g, n1b, wqkvT, bq, bkv, biasx, wpT, bproj, mrs, x1);
  k_mlp<<<4608, 512, 0, stream>>>(x1, mrs, n2g, n2b, w1T, b1, dwk, dwb, w2T, b2, outp);
}